// Round 2
// baseline (889.361 us; speedup 1.0000x reference)
//
#include <hip/hip_runtime.h>

typedef _Float16 half8 __attribute__((ext_vector_type(8)));
typedef _Float16 half4 __attribute__((ext_vector_type(4)));
typedef float f32x4 __attribute__((ext_vector_type(4)));

// async global->LDS 16B: LDS dest must be wave-uniform base + lane*16.
__device__ __forceinline__ void gl2lds16(const _Float16* g, _Float16* l) {
  __builtin_amdgcn_global_load_lds((const __attribute__((address_space(1))) void*)g,
                                   (__attribute__((address_space(3))) void*)l, 16, 0, 0);
}

__device__ __forceinline__ void nt_store4(float* p, f32x4 v) {
  __builtin_nontemporal_store(v, (f32x4*)p);
}

// ---------------- fp32 -> fp16 convert ----------------
__global__ __launch_bounds__(256) void cvt_kernel(const float* __restrict__ in,
                                                  _Float16* __restrict__ out, int n) {
  int i = (blockIdx.x * 256 + threadIdx.x) * 8;
  if (i >= n) return;
  float4 a = *(const float4*)(in + i);
  float4 b = *(const float4*)(in + i + 4);
  half8 o;
  o[0] = (_Float16)a.x; o[1] = (_Float16)a.y; o[2] = (_Float16)a.z; o[3] = (_Float16)a.w;
  o[4] = (_Float16)b.x; o[5] = (_Float16)b.y; o[6] = (_Float16)b.z; o[7] = (_Float16)b.w;
  *(half8*)(out + i) = o;
}

// ---------- fp32 [K][N] -> fp16 [N][K] transpose+convert, 64x64 tiles ----------
__global__ __launch_bounds__(256) void cvtT_kernel(const float* __restrict__ in,
                                                   _Float16* __restrict__ out,
                                                   int K, int N) {
  __shared__ float Ts[64][65];
  const int k0 = blockIdx.y * 64, n0 = blockIdx.x * 64;
  const int t = threadIdx.x;
  const int r = t >> 4, c = (t & 15) * 4;
#pragma unroll
  for (int i = 0; i < 4; i++) {
    float4 v = *(const float4*)(in + (size_t)(k0 + r + i * 16) * N + n0 + c);
    Ts[r + i * 16][c] = v.x; Ts[r + i * 16][c + 1] = v.y;
    Ts[r + i * 16][c + 2] = v.z; Ts[r + i * 16][c + 3] = v.w;
  }
  __syncthreads();
  const int nl = t >> 2, kq = (t & 3) * 16;
  half8 o0, o1;
#pragma unroll
  for (int j = 0; j < 8; j++) {
    o0[j] = (_Float16)Ts[kq + j][nl];
    o1[j] = (_Float16)Ts[kq + 8 + j][nl];
  }
  *(half8*)(out + (size_t)(n0 + nl) * K + k0 + kq) = o0;
  *(half8*)(out + (size_t)(n0 + nl) * K + k0 + kq + 8) = o1;
}

// ---------- V [bh][s][64] -> V^T [bh][64][s] fp16 transpose, 64x64 tiles ----------
__global__ __launch_bounds__(256) void vtrans_kernel(const _Float16* __restrict__ v,
                                                     _Float16* __restrict__ vt) {
  __shared__ _Float16 Ht[64][72];
  const int s0 = blockIdx.x * 64;
  const _Float16* vb = v + (size_t)blockIdx.y * 131072;
  _Float16* vtb = vt + (size_t)blockIdx.y * 131072;
  const int t = threadIdx.x;
  const int sl = t >> 3, dq = (t & 7) * 8;
  *(half8*)&Ht[sl][dq] = *(const half8*)(vb + (s0 + sl) * 64 + dq);
  *(half8*)&Ht[sl + 32][dq] = *(const half8*)(vb + (s0 + sl + 32) * 64 + dq);
  __syncthreads();
  const int dl = t >> 2, sq = (t & 3) * 16;
  half8 o0, o1;
#pragma unroll
  for (int j = 0; j < 8; j++) {
    o0[j] = Ht[sq + j][dl];
    o1[j] = Ht[sq + 8 + j][dl];
  }
  *(half8*)(vtb + (size_t)dl * 2048 + s0 + sq) = o0;
  *(half8*)(vtb + (size_t)dl * 2048 + s0 + sq + 8) = o1;
}

// ---------------- m97-style f16 MFMA GEMM, B pre-transposed [N][K] ----------------
// MODE 1 epilogue pre-scales Q (which==0) by 0.125 = 1/sqrt(64), exact pow2,
// so the attention kernel's softmax logits need no per-element scale.
template <int MODE, int BN>
__global__ __launch_bounds__(256) void gemm16(const _Float16* __restrict__ A,
                                              const _Float16* __restrict__ B,
                                              float* __restrict__ Cf,
                                              _Float16* __restrict__ Ch,
                                              int M, int N, int K) {
  constexpr int MI = (BN == 128) ? 4 : 2;
  __shared__ __align__(16) _Float16 As[128 * 32];
  __shared__ __align__(16) _Float16 Bs[BN * 32];
  const int tid = threadIdx.x;
  const int lane = tid & 63;
  const int wid = tid >> 6;
  const int quad = lane >> 4;
  const int l16 = lane & 15;
  const int mbase = (BN == 128) ? (wid >> 1) * 64 : wid * 32;
  const int nbase = (BN == 128) ? (wid & 1) * 64 : 0;
  const int m0 = blockIdx.y * 128;
  const int n0 = blockIdx.x * BN;

  f32x4 acc[MI][4];
  const f32x4 fz = {0.f, 0.f, 0.f, 0.f};
#pragma unroll
  for (int i = 0; i < MI; i++)
#pragma unroll
    for (int j = 0; j < 4; j++) acc[i][j] = fz;

  const int srow = tid >> 2;
  const int kq = (tid & 3) * 8;

  for (int kt = 0; kt < K; kt += 32) {
    gl2lds16(A + (size_t)(m0 + srow) * K + kt + kq, &As[tid * 8]);
    gl2lds16(A + (size_t)(m0 + 64 + srow) * K + kt + kq, &As[2048 + tid * 8]);
    gl2lds16(B + (size_t)(n0 + srow) * K + kt + kq, &Bs[tid * 8]);
    if (BN == 128)
      gl2lds16(B + (size_t)(n0 + 64 + srow) * K + kt + kq, &Bs[2048 + tid * 8]);
    __syncthreads();
    half8 af[MI], bf[4];
#pragma unroll
    for (int mi = 0; mi < MI; mi++)
      af[mi] = *(const half8*)&As[(mbase + mi * 16 + l16) * 32 + quad * 8];
#pragma unroll
    for (int ni = 0; ni < 4; ni++)
      bf[ni] = *(const half8*)&Bs[(nbase + ni * 16 + l16) * 32 + quad * 8];
#pragma unroll
    for (int mi = 0; mi < MI; mi++)
#pragma unroll
      for (int ni = 0; ni < 4; ni++)
        acc[mi][ni] = __builtin_amdgcn_mfma_f32_16x16x32_f16(af[mi], bf[ni], acc[mi][ni], 0, 0, 0);
    __syncthreads();
  }

#pragma unroll
  for (int mi = 0; mi < MI; mi++)
#pragma unroll
    for (int ni = 0; ni < 4; ni++)
#pragma unroll
      for (int r = 0; r < 4; r++) {
        int row = m0 + mbase + mi * 16 + quad * 4 + r;
        int col = n0 + nbase + ni * 16 + l16;
        float v = acc[mi][ni][r];
        if (MODE == 0) {
          Cf[(size_t)row * N + col] = v;
        } else {
          int which = col >> 10, h = (col >> 6) & 15, d = col & 63;
          int b = row >> 11, s = row & 2047;
          if (which == 0) v *= 0.125f;  // fold softmax scale into Q
          Ch[((((size_t)(which * 2 + b) * 16 + h) * 2048) + s) * 64 + d] = (_Float16)v;
        }
      }
}

// ---------------- fused causal attention, barrier-free ----------------
// K/V^T are L2-resident (512 KB per bh, reused by 32 qt-blocks) -> read MFMA
// fragments DIRECTLY from global; no LDS staging, no __syncthreads at all.
// Only LDS use: Ps (P-transpose for the PV A-fragment), wave-private stripes.
// Q pre-scaled by 0.125 in the QKV GEMM epilogue.
__global__ __launch_bounds__(256) void attn_kernel(const _Float16* __restrict__ qkv,
                                                   const _Float16* __restrict__ vt,
                                                   float* __restrict__ w_out,
                                                   _Float16* __restrict__ o_buf) {
  const int qt = 31 - blockIdx.x;  // heavy blocks launch first
  const int bh = blockIdx.y;
  const int tid = threadIdx.x;
  const int lane = tid & 63;
  const int wid = tid >> 6;
  const int quad = lane >> 4;
  const int l16 = lane & 15;

  const _Float16* qp = qkv + (size_t)bh * 131072;
  const _Float16* kp = qp + 4194304;
  const _Float16* vtb = vt + (size_t)bh * 131072;

  __shared__ __align__(16) _Float16 Ps[64][72];

  const int qrow = qt * 64 + wid * 16 + l16;
  const half8 qa0 = *(const half8*)(qp + qrow * 64 + quad * 8);
  const half8 qa1 = *(const half8*)(qp + qrow * 64 + 32 + quad * 8);

  const f32x4 fz = {0.f, 0.f, 0.f, 0.f};
  const int lrow0 = wid * 16 + quad * 4;

  float* wbase = w_out + (size_t)bh * 4194304 + (size_t)qt * 131072;

  // ---- zerofill above-diagonal: nontemporal streaming stores, no reuse ----
  {
    const int rr = tid >> 4, cc = (tid & 15) * 4;
    for (int kt = qt + 1; kt < 32; kt++) {
      float* wz = wbase + (size_t)kt * 64 + cc;
#pragma unroll
      for (int p = 0; p < 4; p++)
        nt_store4(wz + (size_t)(p * 16 + rr) * 2048, fz);
    }
  }

  float lsum[4] = {0.f, 0.f, 0.f, 0.f};

  // ---- pass 1: row sums of exp(s); K frags straight from L2 ----
  for (int kt = 0; kt <= qt; kt++) {
    const _Float16* kb = kp + (size_t)kt * 4096;
    f32x4 sacc[4];
    __builtin_amdgcn_s_setprio(1);
#pragma unroll
    for (int ni = 0; ni < 4; ni++) {
      half8 kb0 = *(const half8*)(kb + (ni * 16 + l16) * 64 + quad * 8);
      half8 kb1 = *(const half8*)(kb + (ni * 16 + l16) * 64 + 32 + quad * 8);
      f32x4 s = fz;
      s = __builtin_amdgcn_mfma_f32_16x16x32_f16(qa0, kb0, s, 0, 0, 0);
      s = __builtin_amdgcn_mfma_f32_16x16x32_f16(qa1, kb1, s, 0, 0, 0);
      sacc[ni] = s;
    }
    __builtin_amdgcn_s_setprio(0);
    if (kt < qt) {
#pragma unroll
      for (int ni = 0; ni < 4; ni++)
#pragma unroll
        for (int r = 0; r < 4; r++) lsum[r] += __expf(sacc[ni][r]);
    } else {  // diagonal tile: mask col > row
#pragma unroll
      for (int ni = 0; ni < 4; ni++)
#pragma unroll
        for (int r = 0; r < 4; r++) {
          if (ni * 16 + l16 <= lrow0 + r) lsum[r] += __expf(sacc[ni][r]);
        }
    }
  }
  float invl[4];
#pragma unroll
  for (int r = 0; r < 4; r++) {
    float s = lsum[r];
    s += __shfl_xor(s, 1); s += __shfl_xor(s, 2);
    s += __shfl_xor(s, 4); s += __shfl_xor(s, 8);
    invl[r] = 1.0f / s;
  }

  f32x4 oacc[4];
#pragma unroll
  for (int di = 0; di < 4; di++) oacc[di] = fz;

  // ---- pass 2: recompute S, normalized P -> Ps (wave-private), PV, w export ----
  for (int kt = 0; kt <= qt; kt++) {
    const _Float16* kb = kp + (size_t)kt * 4096;
    f32x4 sacc[4];
    __builtin_amdgcn_s_setprio(1);
#pragma unroll
    for (int ni = 0; ni < 4; ni++) {
      half8 kb0 = *(const half8*)(kb + (ni * 16 + l16) * 64 + quad * 8);
      half8 kb1 = *(const half8*)(kb + (ni * 16 + l16) * 64 + 32 + quad * 8);
      f32x4 s = fz;
      s = __builtin_amdgcn_mfma_f32_16x16x32_f16(qa0, kb0, s, 0, 0, 0);
      s = __builtin_amdgcn_mfma_f32_16x16x32_f16(qa1, kb1, s, 0, 0, 0);
      sacc[ni] = s;
    }
    __builtin_amdgcn_s_setprio(0);
#pragma unroll
    for (int ni = 0; ni < 4; ni++)
#pragma unroll
      for (int r = 0; r < 4; r++) {
        int lrw = lrow0 + r;
        int col = ni * 16 + l16;
        float p = __expf(sacc[ni][r]) * invl[r];
        if (kt == qt && col > lrw) p = 0.0f;
        Ps[lrw][col] = (_Float16)p;  // wave-private stripe; lgkmcnt orders it
      }
    // PV: A-frag from Ps, B-frag (V^T rows) straight from L2
    __builtin_amdgcn_s_setprio(1);
#pragma unroll
    for (int kk = 0; kk < 2; kk++) {
      half8 pa = *(const half8*)&Ps[wid * 16 + l16][kk * 32 + quad * 8];
#pragma unroll
      for (int di = 0; di < 4; di++) {
        half8 vb = *(const half8*)(vtb + (size_t)(di * 16 + l16) * 2048 + kt * 64 + kk * 32 + quad * 8);
        oacc[di] = __builtin_amdgcn_mfma_f32_16x16x32_f16(pa, vb, oacc[di], 0, 0, 0);
      }
    }
    __builtin_amdgcn_s_setprio(0);
    // w export: wave re-reads its own Ps stripe, 4x f32x4 nt stores
    {
      const int erow = lane >> 2;
      const int ec = (lane & 3) * 4;
      const _Float16* prow = &Ps[wid * 16 + erow][0];
      float* wrow = wbase + (size_t)(wid * 16 + erow) * 2048 + kt * 64;
#pragma unroll
      for (int j = 0; j < 4; j++) {
        half4 h = *(const half4*)(prow + j * 16 + ec);
        f32x4 o;
        o[0] = (float)h[0]; o[1] = (float)h[1]; o[2] = (float)h[2]; o[3] = (float)h[3];
        nt_store4(wrow + j * 16 + ec, o);
      }
    }
  }

  const int b = bh >> 4, h = bh & 15;
#pragma unroll
  for (int di = 0; di < 4; di++)
#pragma unroll
    for (int r = 0; r < 4; r++) {
      int s = qt * 64 + lrow0 + r;
      int d = di * 16 + l16;
      o_buf[((size_t)(b * 2048 + s) * 16 + h) * 64 + d] = (_Float16)oacc[di][r];
    }
}

extern "C" void kernel_launch(void* const* d_in, const int* in_sizes, int n_in,
                              void* d_out, int out_size, void* d_ws, size_t ws_size,
                              hipStream_t stream) {
  const float* x = (const float*)d_in[0];
  const float* w_qkv = (const float*)d_in[1];
  const float* w_proj = (const float*)d_in[2];
  float* out = (float*)d_out;
  float* w_attn = out + (size_t)4194304;

  // ws (bytes): x16 0..8M | wqkvT 8..14M | wprojT 14..16M | qkv 16..40M |
  //             vT 40..48M | o 48..56M
  char* ws = (char*)d_ws;
  _Float16* x16 = (_Float16*)ws;
  _Float16* wqkvT = (_Float16*)(ws + (size_t)(8 << 20));
  _Float16* wprojT = (_Float16*)(ws + (size_t)(14 << 20));
  _Float16* qkvb = (_Float16*)(ws + (size_t)(16 << 20));
  _Float16* vT = (_Float16*)(ws + (size_t)(40 << 20));
  _Float16* ob = (_Float16*)(ws + (size_t)(48 << 20));

  cvt_kernel<<<2048, 256, 0, stream>>>(x, x16, 4194304);
  cvtT_kernel<<<dim3(48, 16), 256, 0, stream>>>(w_qkv, wqkvT, 1024, 3072);
  cvtT_kernel<<<dim3(16, 16), 256, 0, stream>>>(w_proj, wprojT, 1024, 1024);

  gemm16<1, 128><<<dim3(24, 32), 256, 0, stream>>>(x16, wqkvT, nullptr, qkvb, 4096, 3072, 1024);
  vtrans_kernel<<<dim3(32, 32), 256, 0, stream>>>(qkvb + (size_t)2 * 4194304, vT);
  attn_kernel<<<dim3(32, 32), 256, 0, stream>>>(qkvb, vT, w_attn, ob);
  gemm16<0, 64><<<dim3(16, 32), 256, 0, stream>>>(ob, wprojT, out, nullptr, 4096, 1024, 1024);
}

// Round 3
// 735.940 us; speedup vs baseline: 1.2085x; 1.2085x over previous
//
#include <hip/hip_runtime.h>

typedef _Float16 half8 __attribute__((ext_vector_type(8)));
typedef _Float16 half4 __attribute__((ext_vector_type(4)));
typedef float f32x4 __attribute__((ext_vector_type(4)));

// async global->LDS 16B: LDS dest must be wave-uniform base + lane*16.
__device__ __forceinline__ void gl2lds16(const _Float16* g, _Float16* l) {
  __builtin_amdgcn_global_load_lds((const __attribute__((address_space(1))) void*)g,
                                   (__attribute__((address_space(3))) void*)l, 16, 0, 0);
}

__device__ __forceinline__ void nt_store4(float* p, f32x4 v) {
  __builtin_nontemporal_store(v, (f32x4*)p);
}

// ---------------- fp32 -> fp16 convert ----------------
__global__ __launch_bounds__(256) void cvt_kernel(const float* __restrict__ in,
                                                  _Float16* __restrict__ out, int n) {
  int i = (blockIdx.x * 256 + threadIdx.x) * 8;
  if (i >= n) return;
  float4 a = *(const float4*)(in + i);
  float4 b = *(const float4*)(in + i + 4);
  half8 o;
  o[0] = (_Float16)a.x; o[1] = (_Float16)a.y; o[2] = (_Float16)a.z; o[3] = (_Float16)a.w;
  o[4] = (_Float16)b.x; o[5] = (_Float16)b.y; o[6] = (_Float16)b.z; o[7] = (_Float16)b.w;
  *(half8*)(out + i) = o;
}

// ---------- fp32 [K][N] -> fp16 [N][K] transpose+convert, 64x64 tiles ----------
__global__ __launch_bounds__(256) void cvtT_kernel(const float* __restrict__ in,
                                                   _Float16* __restrict__ out,
                                                   int K, int N) {
  __shared__ float Ts[64][65];
  const int k0 = blockIdx.y * 64, n0 = blockIdx.x * 64;
  const int t = threadIdx.x;
  const int r = t >> 4, c = (t & 15) * 4;
#pragma unroll
  for (int i = 0; i < 4; i++) {
    float4 v = *(const float4*)(in + (size_t)(k0 + r + i * 16) * N + n0 + c);
    Ts[r + i * 16][c] = v.x; Ts[r + i * 16][c + 1] = v.y;
    Ts[r + i * 16][c + 2] = v.z; Ts[r + i * 16][c + 3] = v.w;
  }
  __syncthreads();
  const int nl = t >> 2, kq = (t & 3) * 16;
  half8 o0, o1;
#pragma unroll
  for (int j = 0; j < 8; j++) {
    o0[j] = (_Float16)Ts[kq + j][nl];
    o1[j] = (_Float16)Ts[kq + 8 + j][nl];
  }
  *(half8*)(out + (size_t)(n0 + nl) * K + k0 + kq) = o0;
  *(half8*)(out + (size_t)(n0 + nl) * K + k0 + kq + 8) = o1;
}

// ---------- V [bh][s][64] -> V^T [bh][64][s] fp16 transpose, 64x64 tiles ----------
__global__ __launch_bounds__(256) void vtrans_kernel(const _Float16* __restrict__ v,
                                                     _Float16* __restrict__ vt) {
  __shared__ _Float16 Ht[64][72];
  const int s0 = blockIdx.x * 64;
  const _Float16* vb = v + (size_t)blockIdx.y * 131072;
  _Float16* vtb = vt + (size_t)blockIdx.y * 131072;
  const int t = threadIdx.x;
  const int sl = t >> 3, dq = (t & 7) * 8;
  *(half8*)&Ht[sl][dq] = *(const half8*)(vb + (s0 + sl) * 64 + dq);
  *(half8*)&Ht[sl + 32][dq] = *(const half8*)(vb + (s0 + sl + 32) * 64 + dq);
  __syncthreads();
  const int dl = t >> 2, sq = (t & 3) * 16;
  half8 o0, o1;
#pragma unroll
  for (int j = 0; j < 8; j++) {
    o0[j] = Ht[sq + j][dl];
    o1[j] = Ht[sq + 8 + j][dl];
  }
  *(half8*)(vtb + (size_t)dl * 2048 + s0 + sq) = o0;
  *(half8*)(vtb + (size_t)dl * 2048 + s0 + sq + 8) = o1;
}

// ---------------- m97-style f16 MFMA GEMM, B pre-transposed [N][K] ----------------
// MODE 1 epilogue pre-scales Q (which==0) by 0.125 = 1/sqrt(64), exact pow2.
template <int MODE, int BN>
__global__ __launch_bounds__(256) void gemm16(const _Float16* __restrict__ A,
                                              const _Float16* __restrict__ B,
                                              float* __restrict__ Cf,
                                              _Float16* __restrict__ Ch,
                                              int M, int N, int K) {
  constexpr int MI = (BN == 128) ? 4 : 2;
  __shared__ __align__(16) _Float16 As[128 * 32];
  __shared__ __align__(16) _Float16 Bs[BN * 32];
  const int tid = threadIdx.x;
  const int lane = tid & 63;
  const int wid = tid >> 6;
  const int quad = lane >> 4;
  const int l16 = lane & 15;
  const int mbase = (BN == 128) ? (wid >> 1) * 64 : wid * 32;
  const int nbase = (BN == 128) ? (wid & 1) * 64 : 0;
  const int m0 = blockIdx.y * 128;
  const int n0 = blockIdx.x * BN;

  f32x4 acc[MI][4];
  const f32x4 fz = {0.f, 0.f, 0.f, 0.f};
#pragma unroll
  for (int i = 0; i < MI; i++)
#pragma unroll
    for (int j = 0; j < 4; j++) acc[i][j] = fz;

  const int srow = tid >> 2;
  const int kq = (tid & 3) * 8;

  for (int kt = 0; kt < K; kt += 32) {
    gl2lds16(A + (size_t)(m0 + srow) * K + kt + kq, &As[tid * 8]);
    gl2lds16(A + (size_t)(m0 + 64 + srow) * K + kt + kq, &As[2048 + tid * 8]);
    gl2lds16(B + (size_t)(n0 + srow) * K + kt + kq, &Bs[tid * 8]);
    if (BN == 128)
      gl2lds16(B + (size_t)(n0 + 64 + srow) * K + kt + kq, &Bs[2048 + tid * 8]);
    __syncthreads();
    half8 af[MI], bf[4];
#pragma unroll
    for (int mi = 0; mi < MI; mi++)
      af[mi] = *(const half8*)&As[(mbase + mi * 16 + l16) * 32 + quad * 8];
#pragma unroll
    for (int ni = 0; ni < 4; ni++)
      bf[ni] = *(const half8*)&Bs[(nbase + ni * 16 + l16) * 32 + quad * 8];
#pragma unroll
    for (int mi = 0; mi < MI; mi++)
#pragma unroll
      for (int ni = 0; ni < 4; ni++)
        acc[mi][ni] = __builtin_amdgcn_mfma_f32_16x16x32_f16(af[mi], bf[ni], acc[mi][ni], 0, 0, 0);
    __syncthreads();
  }

#pragma unroll
  for (int mi = 0; mi < MI; mi++)
#pragma unroll
    for (int ni = 0; ni < 4; ni++)
#pragma unroll
      for (int r = 0; r < 4; r++) {
        int row = m0 + mbase + mi * 16 + quad * 4 + r;
        int col = n0 + nbase + ni * 16 + l16;
        float v = acc[mi][ni][r];
        if (MODE == 0) {
          Cf[(size_t)row * N + col] = v;
        } else {
          int which = col >> 10, h = (col >> 6) & 15, d = col & 63;
          int b = row >> 11, s = row & 2047;
          if (which == 0) v *= 0.125f;  // fold softmax scale into Q
          Ch[((((size_t)(which * 2 + b) * 16 + h) * 2048) + s) * 64 + d] = (_Float16)v;
        }
      }
}

// ---------------- fused causal attention ----------------
// R1 staged structure + three fixes:
//  (1) V^T fragments prefetched into REGISTERS at tile top (T14) — no Vs LDS,
//      latency hidden under QK+softmax, LDS 41->25KB (occupancy up).
//  (2) w export moved AFTER the per-tile barrier: nt stores stay outstanding
//      through the next tile's compute instead of draining at vmcnt(0) each tile.
//  (3) Q pre-scaled by 0.125 in the QKV GEMM epilogue (no per-element scale here).
__global__ __launch_bounds__(256) void attn_kernel(const _Float16* __restrict__ qkv,
                                                   const _Float16* __restrict__ vt,
                                                   float* __restrict__ w_out,
                                                   _Float16* __restrict__ o_buf) {
  const int qt = 31 - blockIdx.x;  // heavy blocks launch first
  const int bh = blockIdx.y;
  const int tid = threadIdx.x;
  const int lane = tid & 63;
  const int wid = tid >> 6;
  const int quad = lane >> 4;
  const int l16 = lane & 15;

  const _Float16* qp = qkv + (size_t)bh * 131072;
  const _Float16* kp = qp + 4194304;
  const _Float16* vtb = vt + (size_t)bh * 131072;

  __shared__ __align__(16) _Float16 Ks[2][4096];  // [buf][chunk d0/d1][s][32]
  __shared__ __align__(16) _Float16 Ps[64][72];   // wave-private stripes

  const int qrow = qt * 64 + wid * 16 + l16;
  const half8 qa0 = *(const half8*)(qp + qrow * 64 + quad * 8);
  const half8 qa1 = *(const half8*)(qp + qrow * 64 + 32 + quad * 8);

  const int srow = tid >> 2;        // 0..63
  const int blk8 = (tid & 3) * 8;
  const f32x4 fz = {0.f, 0.f, 0.f, 0.f};
  const int lrow0 = wid * 16 + quad * 4;

  float* wbase = w_out + (size_t)bh * 4194304 + (size_t)qt * 131072;

  // ---- zerofill above-diagonal: nt streaming stores, drain at first barrier ----
  {
    const int rr = tid >> 4, cc = (tid & 15) * 4;
    for (int kt = qt + 1; kt < 32; kt++) {
      float* wz = wbase + (size_t)kt * 64 + cc;
#pragma unroll
      for (int p = 0; p < 4; p++)
        nt_store4(wz + (size_t)(p * 16 + rr) * 2048, fz);
    }
  }

  float lsum[4] = {0.f, 0.f, 0.f, 0.f};

  // ---- pass 1: row sums of exp(s); K staged via gl2lds, 2-deep ----
  int cur = 0;
  gl2lds16(kp + (size_t)srow * 64 + blk8, &Ks[0][tid * 8]);
  gl2lds16(kp + (size_t)srow * 64 + 32 + blk8, &Ks[0][2048 + tid * 8]);
  __syncthreads();
  for (int kt = 0; kt <= qt; kt++) {
    if (kt < qt) {
      gl2lds16(kp + (size_t)((kt + 1) * 64 + srow) * 64 + blk8, &Ks[cur ^ 1][tid * 8]);
      gl2lds16(kp + (size_t)((kt + 1) * 64 + srow) * 64 + 32 + blk8, &Ks[cur ^ 1][2048 + tid * 8]);
    }
    f32x4 sacc[4];
#pragma unroll
    for (int ni = 0; ni < 4; ni++) {
      half8 kb0 = *(const half8*)&Ks[cur][(ni * 16 + l16) * 32 + quad * 8];
      half8 kb1 = *(const half8*)&Ks[cur][2048 + (ni * 16 + l16) * 32 + quad * 8];
      f32x4 s = fz;
      s = __builtin_amdgcn_mfma_f32_16x16x32_f16(qa0, kb0, s, 0, 0, 0);
      s = __builtin_amdgcn_mfma_f32_16x16x32_f16(qa1, kb1, s, 0, 0, 0);
      sacc[ni] = s;
    }
    if (kt < qt) {
#pragma unroll
      for (int ni = 0; ni < 4; ni++)
#pragma unroll
        for (int r = 0; r < 4; r++) lsum[r] += __expf(sacc[ni][r]);
    } else {  // diagonal tile: mask col > row
#pragma unroll
      for (int ni = 0; ni < 4; ni++)
#pragma unroll
        for (int r = 0; r < 4; r++) {
          if (ni * 16 + l16 <= lrow0 + r) lsum[r] += __expf(sacc[ni][r]);
        }
    }
    __syncthreads();
    cur ^= 1;
  }
  float invl[4];
#pragma unroll
  for (int r = 0; r < 4; r++) {
    float s = lsum[r];
    s += __shfl_xor(s, 1); s += __shfl_xor(s, 2);
    s += __shfl_xor(s, 4); s += __shfl_xor(s, 8);
    invl[r] = 1.0f / s;
  }

  f32x4 oacc[4];
#pragma unroll
  for (int di = 0; di < 4; di++) oacc[di] = fz;

  // ---- pass 2: K staged in LDS; V^T fragments prefetched to registers ----
  cur = 0;
  gl2lds16(kp + (size_t)srow * 64 + blk8, &Ks[0][tid * 8]);
  gl2lds16(kp + (size_t)srow * 64 + 32 + blk8, &Ks[0][2048 + tid * 8]);
  __syncthreads();
  for (int kt = 0; kt <= qt; kt++) {
    // V register prefetch: issued now, consumed after QK+softmax (latency hidden)
    half8 vr[2][4];
#pragma unroll
    for (int kk = 0; kk < 2; kk++)
#pragma unroll
      for (int di = 0; di < 4; di++)
        vr[kk][di] = *(const half8*)(vtb + (size_t)(di * 16 + l16) * 2048 + kt * 64 + kk * 32 + quad * 8);
    if (kt < qt) {
      gl2lds16(kp + (size_t)((kt + 1) * 64 + srow) * 64 + blk8, &Ks[cur ^ 1][tid * 8]);
      gl2lds16(kp + (size_t)((kt + 1) * 64 + srow) * 64 + 32 + blk8, &Ks[cur ^ 1][2048 + tid * 8]);
    }
    f32x4 sacc[4];
#pragma unroll
    for (int ni = 0; ni < 4; ni++) {
      half8 kb0 = *(const half8*)&Ks[cur][(ni * 16 + l16) * 32 + quad * 8];
      half8 kb1 = *(const half8*)&Ks[cur][2048 + (ni * 16 + l16) * 32 + quad * 8];
      f32x4 s = fz;
      s = __builtin_amdgcn_mfma_f32_16x16x32_f16(qa0, kb0, s, 0, 0, 0);
      s = __builtin_amdgcn_mfma_f32_16x16x32_f16(qa1, kb1, s, 0, 0, 0);
      sacc[ni] = s;
    }
#pragma unroll
    for (int ni = 0; ni < 4; ni++)
#pragma unroll
      for (int r = 0; r < 4; r++) {
        int lrw = lrow0 + r;
        int col = ni * 16 + l16;
        float p = __expf(sacc[ni][r]) * invl[r];
        if (kt == qt && col > lrw) p = 0.0f;
        Ps[lrw][col] = (_Float16)p;  // wave-private stripe
      }
    // PV: A-frag from Ps (own stripe), B-frag from registers
#pragma unroll
    for (int kk = 0; kk < 2; kk++) {
      half8 pa = *(const half8*)&Ps[wid * 16 + l16][kk * 32 + quad * 8];
#pragma unroll
      for (int di = 0; di < 4; di++)
        oacc[di] = __builtin_amdgcn_mfma_f32_16x16x32_f16(pa, vr[kk][di], oacc[di], 0, 0, 0);
    }
    __syncthreads();
    // w export AFTER the barrier: stores stay outstanding into next tile.
    // Ps stripe is wave-private; same-wave LDS ordering protects vs next-tile writes.
    {
      const int erow = lane >> 2;
      const int ec = (lane & 3) * 4;
      const _Float16* prow = &Ps[wid * 16 + erow][0];
      float* wrow = wbase + (size_t)(wid * 16 + erow) * 2048 + kt * 64;
#pragma unroll
      for (int j = 0; j < 4; j++) {
        half4 h = *(const half4*)(prow + j * 16 + ec);
        f32x4 o;
        o[0] = (float)h[0]; o[1] = (float)h[1]; o[2] = (float)h[2]; o[3] = (float)h[3];
        nt_store4(wrow + j * 16 + ec, o);
      }
    }
    cur ^= 1;
  }

  const int b = bh >> 4, h = bh & 15;
#pragma unroll
  for (int di = 0; di < 4; di++)
#pragma unroll
    for (int r = 0; r < 4; r++) {
      int s = qt * 64 + lrow0 + r;
      int d = di * 16 + l16;
      o_buf[((size_t)(b * 2048 + s) * 16 + h) * 64 + d] = (_Float16)oacc[di][r];
    }
}

extern "C" void kernel_launch(void* const* d_in, const int* in_sizes, int n_in,
                              void* d_out, int out_size, void* d_ws, size_t ws_size,
                              hipStream_t stream) {
  const float* x = (const float*)d_in[0];
  const float* w_qkv = (const float*)d_in[1];
  const float* w_proj = (const float*)d_in[2];
  float* out = (float*)d_out;
  float* w_attn = out + (size_t)4194304;

  // ws (bytes): x16 0..8M | wqkvT 8..14M | wprojT 14..16M | qkv 16..40M |
  //             vT 40..48M | o 48..56M
  char* ws = (char*)d_ws;
  _Float16* x16 = (_Float16*)ws;
  _Float16* wqkvT = (_Float16*)(ws + (size_t)(8 << 20));
  _Float16* wprojT = (_Float16*)(ws + (size_t)(14 << 20));
  _Float16* qkvb = (_Float16*)(ws + (size_t)(16 << 20));
  _Float16* vT = (_Float16*)(ws + (size_t)(40 << 20));
  _Float16* ob = (_Float16*)(ws + (size_t)(48 << 20));

  cvt_kernel<<<2048, 256, 0, stream>>>(x, x16, 4194304);
  cvtT_kernel<<<dim3(48, 16), 256, 0, stream>>>(w_qkv, wqkvT, 1024, 3072);
  cvtT_kernel<<<dim3(16, 16), 256, 0, stream>>>(w_proj, wprojT, 1024, 1024);

  gemm16<1, 128><<<dim3(24, 32), 256, 0, stream>>>(x16, wqkvT, nullptr, qkvb, 4096, 3072, 1024);
  vtrans_kernel<<<dim3(32, 32), 256, 0, stream>>>(qkvb + (size_t)2 * 4194304, vT);
  attn_kernel<<<dim3(32, 32), 256, 0, stream>>>(qkvb, vT, w_attn, ob);
  gemm16<0, 64><<<dim3(16, 32), 256, 0, stream>>>(ob, wprojT, out, nullptr, 4096, 1024, 1024);
}

// Round 6
// 694.863 us; speedup vs baseline: 1.2799x; 1.0591x over previous
//
#include <hip/hip_runtime.h>

typedef _Float16 half8 __attribute__((ext_vector_type(8)));
typedef _Float16 half4 __attribute__((ext_vector_type(4)));
typedef float f32x4 __attribute__((ext_vector_type(4)));

// async global->LDS 16B: LDS dest must be wave-uniform base + lane*16.
__device__ __forceinline__ void gl2lds16(const _Float16* g, _Float16* l) {
  __builtin_amdgcn_global_load_lds((const __attribute__((address_space(1))) void*)g,
                                   (__attribute__((address_space(3))) void*)l, 16, 0, 0);
}

__device__ __forceinline__ void nt_store4(float* p, f32x4 v) {
  __builtin_nontemporal_store(v, (f32x4*)p);
}

// ---------------- fp32 -> fp16 convert ----------------
__global__ __launch_bounds__(256) void cvt_kernel(const float* __restrict__ in,
                                                  _Float16* __restrict__ out, int n) {
  int i = (blockIdx.x * 256 + threadIdx.x) * 8;
  if (i >= n) return;
  float4 a = *(const float4*)(in + i);
  float4 b = *(const float4*)(in + i + 4);
  half8 o;
  o[0] = (_Float16)a.x; o[1] = (_Float16)a.y; o[2] = (_Float16)a.z; o[3] = (_Float16)a.w;
  o[4] = (_Float16)b.x; o[5] = (_Float16)b.y; o[6] = (_Float16)b.z; o[7] = (_Float16)b.w;
  *(half8*)(out + i) = o;
}

// ---------- fp32 [K][N] -> fp16 [N][K] transpose+convert, 64x64 tiles ----------
__global__ __launch_bounds__(256) void cvtT_kernel(const float* __restrict__ in,
                                                   _Float16* __restrict__ out,
                                                   int K, int N) {
  __shared__ float Ts[64][65];
  const int k0 = blockIdx.y * 64, n0 = blockIdx.x * 64;
  const int t = threadIdx.x;
  const int r = t >> 4, c = (t & 15) * 4;
#pragma unroll
  for (int i = 0; i < 4; i++) {
    float4 v = *(const float4*)(in + (size_t)(k0 + r + i * 16) * N + n0 + c);
    Ts[r + i * 16][c] = v.x; Ts[r + i * 16][c + 1] = v.y;
    Ts[r + i * 16][c + 2] = v.z; Ts[r + i * 16][c + 3] = v.w;
  }
  __syncthreads();
  const int nl = t >> 2, kq = (t & 3) * 16;
  half8 o0, o1;
#pragma unroll
  for (int j = 0; j < 8; j++) {
    o0[j] = (_Float16)Ts[kq + j][nl];
    o1[j] = (_Float16)Ts[kq + 8 + j][nl];
  }
  *(half8*)(out + (size_t)(n0 + nl) * K + k0 + kq) = o0;
  *(half8*)(out + (size_t)(n0 + nl) * K + k0 + kq + 8) = o1;
}

// ---------- V [bh][s][64] -> V^T [bh][64][s] fp16 transpose, 64x64 tiles ----------
__global__ __launch_bounds__(256) void vtrans_kernel(const _Float16* __restrict__ v,
                                                     _Float16* __restrict__ vt) {
  __shared__ _Float16 Ht[64][72];
  const int s0 = blockIdx.x * 64;
  const _Float16* vb = v + (size_t)blockIdx.y * 131072;
  _Float16* vtb = vt + (size_t)blockIdx.y * 131072;
  const int t = threadIdx.x;
  const int sl = t >> 3, dq = (t & 7) * 8;
  *(half8*)&Ht[sl][dq] = *(const half8*)(vb + (s0 + sl) * 64 + dq);
  *(half8*)&Ht[sl + 32][dq] = *(const half8*)(vb + (s0 + sl + 32) * 64 + dq);
  __syncthreads();
  const int dl = t >> 2, sq = (t & 3) * 16;
  half8 o0, o1;
#pragma unroll
  for (int j = 0; j < 8; j++) {
    o0[j] = Ht[sq + j][dl];
    o1[j] = Ht[sq + 8 + j][dl];
  }
  *(half8*)(vtb + (size_t)dl * 2048 + s0 + sq) = o0;
  *(half8*)(vtb + (size_t)dl * 2048 + s0 + sq + 8) = o1;
}

// ---------------- m97-style f16 MFMA GEMM, B pre-transposed [N][K] ----------------
// MODE 1 epilogue pre-scales Q (which==0) by 0.125 = 1/sqrt(64), exact pow2.
template <int MODE, int BN>
__global__ __launch_bounds__(256) void gemm16(const _Float16* __restrict__ A,
                                              const _Float16* __restrict__ B,
                                              float* __restrict__ Cf,
                                              _Float16* __restrict__ Ch,
                                              int M, int N, int K) {
  constexpr int MI = (BN == 128) ? 4 : 2;
  __shared__ __align__(16) _Float16 As[128 * 32];
  __shared__ __align__(16) _Float16 Bs[BN * 32];
  const int tid = threadIdx.x;
  const int lane = tid & 63;
  const int wid = tid >> 6;
  const int quad = lane >> 4;
  const int l16 = lane & 15;
  const int mbase = (BN == 128) ? (wid >> 1) * 64 : wid * 32;
  const int nbase = (BN == 128) ? (wid & 1) * 64 : 0;
  const int m0 = blockIdx.y * 128;
  const int n0 = blockIdx.x * BN;

  f32x4 acc[MI][4];
  const f32x4 fz = {0.f, 0.f, 0.f, 0.f};
#pragma unroll
  for (int i = 0; i < MI; i++)
#pragma unroll
    for (int j = 0; j < 4; j++) acc[i][j] = fz;

  const int srow = tid >> 2;
  const int kq = (tid & 3) * 8;

  for (int kt = 0; kt < K; kt += 32) {
    gl2lds16(A + (size_t)(m0 + srow) * K + kt + kq, &As[tid * 8]);
    gl2lds16(A + (size_t)(m0 + 64 + srow) * K + kt + kq, &As[2048 + tid * 8]);
    gl2lds16(B + (size_t)(n0 + srow) * K + kt + kq, &Bs[tid * 8]);
    if (BN == 128)
      gl2lds16(B + (size_t)(n0 + 64 + srow) * K + kt + kq, &Bs[2048 + tid * 8]);
    __syncthreads();
    half8 af[MI], bf[4];
#pragma unroll
    for (int mi = 0; mi < MI; mi++)
      af[mi] = *(const half8*)&As[(mbase + mi * 16 + l16) * 32 + quad * 8];
#pragma unroll
    for (int ni = 0; ni < 4; ni++)
      bf[ni] = *(const half8*)&Bs[(nbase + ni * 16 + l16) * 32 + quad * 8];
#pragma unroll
    for (int mi = 0; mi < MI; mi++)
#pragma unroll
      for (int ni = 0; ni < 4; ni++)
        acc[mi][ni] = __builtin_amdgcn_mfma_f32_16x16x32_f16(af[mi], bf[ni], acc[mi][ni], 0, 0, 0);
    __syncthreads();
  }

#pragma unroll
  for (int mi = 0; mi < MI; mi++)
#pragma unroll
    for (int ni = 0; ni < 4; ni++)
#pragma unroll
      for (int r = 0; r < 4; r++) {
        int row = m0 + mbase + mi * 16 + quad * 4 + r;
        int col = n0 + nbase + ni * 16 + l16;
        float v = acc[mi][ni][r];
        if (MODE == 0) {
          Cf[(size_t)row * N + col] = v;
        } else {
          int which = col >> 10, h = (col >> 6) & 15, d = col & 63;
          int b = row >> 11, s = row & 2047;
          if (which == 0) v *= 0.125f;  // fold softmax scale into Q
          Ch[((((size_t)(which * 2 + b) * 16 + h) * 2048) + s) * 64 + d] = (_Float16)v;
        }
      }
}

// ---------------- fused causal attention ----------------
// R1 staged structure (K+V dbuf via gl2lds, export pre-barrier) with swapped-
// operand QK^T: sacc = mfma(K_frag, Q_frag) = S^T fragment, so each lane owns
// ONE q row (q = wid*16+l16) and 16 k values (k = ni*16+quad*4+r). Gains:
//  - Ps writes: 4x half4 ds_write_b64 per tile (was 16 scalar ds_write_b16)
//  - pass-1 row sum is a scalar per lane; reduce = 2 shuffles (was 4)
//  - Q pre-scaled by 0.125 in QKV GEMM epilogue (no per-element scale here)
__global__ __launch_bounds__(256) void attn_kernel(const _Float16* __restrict__ qkv,
                                                   const _Float16* __restrict__ vt,
                                                   float* __restrict__ w_out,
                                                   _Float16* __restrict__ o_buf) {
  const int qt = 31 - blockIdx.x;  // heavy blocks launch first
  const int bh = blockIdx.y;
  const int tid = threadIdx.x;
  const int lane = tid & 63;
  const int wid = tid >> 6;
  const int quad = lane >> 4;
  const int l16 = lane & 15;

  const _Float16* qp = qkv + (size_t)bh * 131072;
  const _Float16* kp = qp + 4194304;
  const _Float16* vtb = vt + (size_t)bh * 131072;

  __shared__ __align__(16) _Float16 Ks[2][4096];  // [buf][chunk d0/d1][s][32]
  __shared__ __align__(16) _Float16 Vs[2][4096];  // [buf][chunk s0/s1][d][32]
  __shared__ __align__(16) _Float16 Ps[64][72];   // wave-private stripes

  const int qrow = qt * 64 + wid * 16 + l16;
  const half8 qa0 = *(const half8*)(qp + qrow * 64 + quad * 8);
  const half8 qa1 = *(const half8*)(qp + qrow * 64 + 32 + quad * 8);

  const int srow = tid >> 2;        // 0..63
  const int blk8 = (tid & 3) * 8;
  const f32x4 fz = {0.f, 0.f, 0.f, 0.f};
  const int qloc = wid * 16 + l16;  // this lane's q row within the 64-row tile
  const int kbase = quad * 4;       // this lane's k sub-offset within a 16-col block

  float* wbase = w_out + (size_t)bh * 4194304 + (size_t)qt * 131072;

  // ---- zerofill above-diagonal: nt streaming stores ----
  {
    const int rr = tid >> 4, cc = (tid & 15) * 4;
    for (int kt = qt + 1; kt < 32; kt++) {
      float* wz = wbase + (size_t)kt * 64 + cc;
#pragma unroll
      for (int p = 0; p < 4; p++)
        nt_store4(wz + (size_t)(p * 16 + rr) * 2048, fz);
    }
  }

  float lsum = 0.f;

  // ---- pass 1: row sums of exp(s); K staged via gl2lds, 2-deep ----
  int cur = 0;
  gl2lds16(kp + (size_t)srow * 64 + blk8, &Ks[0][tid * 8]);
  gl2lds16(kp + (size_t)srow * 64 + 32 + blk8, &Ks[0][2048 + tid * 8]);
  __syncthreads();
  for (int kt = 0; kt <= qt; kt++) {
    if (kt < qt) {
      gl2lds16(kp + (size_t)((kt + 1) * 64 + srow) * 64 + blk8, &Ks[cur ^ 1][tid * 8]);
      gl2lds16(kp + (size_t)((kt + 1) * 64 + srow) * 64 + 32 + blk8, &Ks[cur ^ 1][2048 + tid * 8]);
    }
    f32x4 sacc[4];
#pragma unroll
    for (int ni = 0; ni < 4; ni++) {
      half8 kb0 = *(const half8*)&Ks[cur][(ni * 16 + l16) * 32 + quad * 8];
      half8 kb1 = *(const half8*)&Ks[cur][2048 + (ni * 16 + l16) * 32 + quad * 8];
      f32x4 s = fz;
      s = __builtin_amdgcn_mfma_f32_16x16x32_f16(kb0, qa0, s, 0, 0, 0);  // swapped: S^T
      s = __builtin_amdgcn_mfma_f32_16x16x32_f16(kb1, qa1, s, 0, 0, 0);
      sacc[ni] = s;
    }
    if (kt < qt) {
#pragma unroll
      for (int ni = 0; ni < 4; ni++)
#pragma unroll
        for (int r = 0; r < 4; r++) lsum += __expf(sacc[ni][r]);
    } else {  // diagonal tile: include only k <= q
#pragma unroll
      for (int ni = 0; ni < 4; ni++)
#pragma unroll
        for (int r = 0; r < 4; r++) {
          if (ni * 16 + kbase + r <= qloc) lsum += __expf(sacc[ni][r]);
        }
    }
    __syncthreads();
    cur ^= 1;
  }
  // reduce over the 4 quads holding the same q row
  lsum += __shfl_xor(lsum, 16);
  lsum += __shfl_xor(lsum, 32);
  const float invl = 1.0f / lsum;

  f32x4 oacc[4];
#pragma unroll
  for (int di = 0; di < 4; di++) oacc[di] = fz;

  // ---- pass 2: recompute S^T, normalized P -> Ps (half4 packs), PV, export ----
  cur = 0;
  gl2lds16(kp + (size_t)srow * 64 + blk8, &Ks[0][tid * 8]);
  gl2lds16(kp + (size_t)srow * 64 + 32 + blk8, &Ks[0][2048 + tid * 8]);
  gl2lds16(vtb + (size_t)srow * 2048 + blk8, &Vs[0][tid * 8]);
  gl2lds16(vtb + (size_t)srow * 2048 + 32 + blk8, &Vs[0][2048 + tid * 8]);
  __syncthreads();
  for (int kt = 0; kt <= qt; kt++) {
    if (kt < qt) {
      const int kn = kt + 1;
      gl2lds16(kp + (size_t)(kn * 64 + srow) * 64 + blk8, &Ks[cur ^ 1][tid * 8]);
      gl2lds16(kp + (size_t)(kn * 64 + srow) * 64 + 32 + blk8, &Ks[cur ^ 1][2048 + tid * 8]);
      gl2lds16(vtb + (size_t)srow * 2048 + kn * 64 + blk8, &Vs[cur ^ 1][tid * 8]);
      gl2lds16(vtb + (size_t)srow * 2048 + kn * 64 + 32 + blk8, &Vs[cur ^ 1][2048 + tid * 8]);
    }
    f32x4 sacc[4];
#pragma unroll
    for (int ni = 0; ni < 4; ni++) {
      half8 kb0 = *(const half8*)&Ks[cur][(ni * 16 + l16) * 32 + quad * 8];
      half8 kb1 = *(const half8*)&Ks[cur][2048 + (ni * 16 + l16) * 32 + quad * 8];
      f32x4 s = fz;
      s = __builtin_amdgcn_mfma_f32_16x16x32_f16(kb0, qa0, s, 0, 0, 0);  // swapped: S^T
      s = __builtin_amdgcn_mfma_f32_16x16x32_f16(kb1, qa1, s, 0, 0, 0);
      sacc[ni] = s;
    }
    const bool diag = (kt == qt);
#pragma unroll
    for (int ni = 0; ni < 4; ni++) {
      half4 ph;
#pragma unroll
      for (int r = 0; r < 4; r++) {
        float p = __expf(sacc[ni][r]) * invl;
        if (diag && (ni * 16 + kbase + r > qloc)) p = 0.0f;
        ph[r] = (_Float16)p;
      }
      *(half4*)&Ps[qloc][ni * 16 + kbase] = ph;  // wave-private row, packed write
    }
    // PV: A-frag from Ps (own stripe), B-frag from Vs
#pragma unroll
    for (int kk = 0; kk < 2; kk++) {
      half8 pa = *(const half8*)&Ps[wid * 16 + l16][kk * 32 + quad * 8];
#pragma unroll
      for (int di = 0; di < 4; di++) {
        half8 vb = *(const half8*)&Vs[cur][kk * 2048 + (di * 16 + l16) * 32 + quad * 8];
        oacc[di] = __builtin_amdgcn_mfma_f32_16x16x32_f16(pa, vb, oacc[di], 0, 0, 0);
      }
    }
    // w export: wave re-reads its own Ps stripe, 4x f32x4 nt stores
    {
      const int erow = lane >> 2;
      const int ec = (lane & 3) * 4;
      const _Float16* prow = &Ps[wid * 16 + erow][0];
      float* wrow = wbase + (size_t)(wid * 16 + erow) * 2048 + kt * 64;
#pragma unroll
      for (int j = 0; j < 4; j++) {
        half4 h = *(const half4*)(prow + j * 16 + ec);
        f32x4 o;
        o[0] = (float)h[0]; o[1] = (float)h[1]; o[2] = (float)h[2]; o[3] = (float)h[3];
        nt_store4(wrow + j * 16 + ec, o);
      }
    }
    __syncthreads();
    cur ^= 1;
  }

  const int b = bh >> 4, h = bh & 15;
#pragma unroll
  for (int di = 0; di < 4; di++)
#pragma unroll
    for (int r = 0; r < 4; r++) {
      int s = qt * 64 + wid * 16 + quad * 4 + r;
      int d = di * 16 + l16;
      o_buf[((size_t)(b * 2048 + s) * 16 + h) * 64 + d] = (_Float16)oacc[di][r];
    }
}

extern "C" void kernel_launch(void* const* d_in, const int* in_sizes, int n_in,
                              void* d_out, int out_size, void* d_ws, size_t ws_size,
                              hipStream_t stream) {
  const float* x = (const float*)d_in[0];
  const float* w_qkv = (const float*)d_in[1];
  const float* w_proj = (const float*)d_in[2];
  float* out = (float*)d_out;
  float* w_attn = out + (size_t)4194304;

  // ws (bytes): x16 0..8M | wqkvT 8..14M | wprojT 14..16M | qkv 16..40M |
  //             vT 40..48M | o 48..56M
  char* ws = (char*)d_ws;
  _Float16* x16 = (_Float16*)ws;
  _Float16* wqkvT = (_Float16*)(ws + (size_t)(8 << 20));
  _Float16* wprojT = (_Float16*)(ws + (size_t)(14 << 20));
  _Float16* qkvb = (_Float16*)(ws + (size_t)(16 << 20));
  _Float16* vT = (_Float16*)(ws + (size_t)(40 << 20));
  _Float16* ob = (_Float16*)(ws + (size_t)(48 << 20));

  cvt_kernel<<<2048, 256, 0, stream>>>(x, x16, 4194304);
  cvtT_kernel<<<dim3(48, 16), 256, 0, stream>>>(w_qkv, wqkvT, 1024, 3072);
  cvtT_kernel<<<dim3(16, 16), 256, 0, stream>>>(w_proj, wprojT, 1024, 1024);

  gemm16<1, 128><<<dim3(24, 32), 256, 0, stream>>>(x16, wqkvT, nullptr, qkvb, 4096, 3072, 1024);
  vtrans_kernel<<<dim3(32, 32), 256, 0, stream>>>(qkvb + (size_t)2 * 4194304, vT);
  attn_kernel<<<dim3(32, 32), 256, 0, stream>>>(qkvb, vT, w_attn, ob);
  gemm16<0, 64><<<dim3(16, 32), 256, 0, stream>>>(ob, wprojT, out, nullptr, 4096, 1024, 1024);
}

// Round 7
// 694.151 us; speedup vs baseline: 1.2812x; 1.0010x over previous
//
#include <hip/hip_runtime.h>

typedef _Float16 half8 __attribute__((ext_vector_type(8)));
typedef _Float16 half4 __attribute__((ext_vector_type(4)));
typedef float f32x4 __attribute__((ext_vector_type(4)));

// async global->LDS 16B: LDS dest must be wave-uniform base + lane*16.
__device__ __forceinline__ void gl2lds16(const _Float16* g, _Float16* l) {
  __builtin_amdgcn_global_load_lds((const __attribute__((address_space(1))) void*)g,
                                   (__attribute__((address_space(3))) void*)l, 16, 0, 0);
}

__device__ __forceinline__ void nt_store4(float* p, f32x4 v) {
  __builtin_nontemporal_store(v, (f32x4*)p);
}

// ---------------- fp32 -> fp16 convert ----------------
__global__ __launch_bounds__(256) void cvt_kernel(const float* __restrict__ in,
                                                  _Float16* __restrict__ out, int n) {
  int i = (blockIdx.x * 256 + threadIdx.x) * 8;
  if (i >= n) return;
  float4 a = *(const float4*)(in + i);
  float4 b = *(const float4*)(in + i + 4);
  half8 o;
  o[0] = (_Float16)a.x; o[1] = (_Float16)a.y; o[2] = (_Float16)a.z; o[3] = (_Float16)a.w;
  o[4] = (_Float16)b.x; o[5] = (_Float16)b.y; o[6] = (_Float16)b.z; o[7] = (_Float16)b.w;
  *(half8*)(out + i) = o;
}

// ---------- fp32 [K][N] -> fp16 [N][K] transpose+convert, 64x64 tiles ----------
__global__ __launch_bounds__(256) void cvtT_kernel(const float* __restrict__ in,
                                                   _Float16* __restrict__ out,
                                                   int K, int N) {
  __shared__ float Ts[64][65];
  const int k0 = blockIdx.y * 64, n0 = blockIdx.x * 64;
  const int t = threadIdx.x;
  const int r = t >> 4, c = (t & 15) * 4;
#pragma unroll
  for (int i = 0; i < 4; i++) {
    float4 v = *(const float4*)(in + (size_t)(k0 + r + i * 16) * N + n0 + c);
    Ts[r + i * 16][c] = v.x; Ts[r + i * 16][c + 1] = v.y;
    Ts[r + i * 16][c + 2] = v.z; Ts[r + i * 16][c + 3] = v.w;
  }
  __syncthreads();
  const int nl = t >> 2, kq = (t & 3) * 16;
  half8 o0, o1;
#pragma unroll
  for (int j = 0; j < 8; j++) {
    o0[j] = (_Float16)Ts[kq + j][nl];
    o1[j] = (_Float16)Ts[kq + 8 + j][nl];
  }
  *(half8*)(out + (size_t)(n0 + nl) * K + k0 + kq) = o0;
  *(half8*)(out + (size_t)(n0 + nl) * K + k0 + kq + 8) = o1;
}

// ---------- V [bh][s][64] -> V^T [bh][64][s] fp16 transpose, 64x64 tiles ----------
__global__ __launch_bounds__(256) void vtrans_kernel(const _Float16* __restrict__ v,
                                                     _Float16* __restrict__ vt) {
  __shared__ _Float16 Ht[64][72];
  const int s0 = blockIdx.x * 64;
  const _Float16* vb = v + (size_t)blockIdx.y * 131072;
  _Float16* vtb = vt + (size_t)blockIdx.y * 131072;
  const int t = threadIdx.x;
  const int sl = t >> 3, dq = (t & 7) * 8;
  *(half8*)&Ht[sl][dq] = *(const half8*)(vb + (s0 + sl) * 64 + dq);
  *(half8*)&Ht[sl + 32][dq] = *(const half8*)(vb + (s0 + sl + 32) * 64 + dq);
  __syncthreads();
  const int dl = t >> 2, sq = (t & 3) * 16;
  half8 o0, o1;
#pragma unroll
  for (int j = 0; j < 8; j++) {
    o0[j] = Ht[sq + j][dl];
    o1[j] = Ht[sq + 8 + j][dl];
  }
  *(half8*)(vtb + (size_t)dl * 2048 + s0 + sq) = o0;
  *(half8*)(vtb + (size_t)dl * 2048 + s0 + sq + 8) = o1;
}

// ---------------- m97-style f16 MFMA GEMM, B pre-transposed [N][K] ----------------
// MODE 1 epilogue pre-scales Q (which==0) by 0.125 = 1/sqrt(64), exact pow2.
template <int MODE, int BN>
__global__ __launch_bounds__(256) void gemm16(const _Float16* __restrict__ A,
                                              const _Float16* __restrict__ B,
                                              float* __restrict__ Cf,
                                              _Float16* __restrict__ Ch,
                                              int M, int N, int K) {
  constexpr int MI = (BN == 128) ? 4 : 2;
  __shared__ __align__(16) _Float16 As[128 * 32];
  __shared__ __align__(16) _Float16 Bs[BN * 32];
  const int tid = threadIdx.x;
  const int lane = tid & 63;
  const int wid = tid >> 6;
  const int quad = lane >> 4;
  const int l16 = lane & 15;
  const int mbase = (BN == 128) ? (wid >> 1) * 64 : wid * 32;
  const int nbase = (BN == 128) ? (wid & 1) * 64 : 0;
  const int m0 = blockIdx.y * 128;
  const int n0 = blockIdx.x * BN;

  f32x4 acc[MI][4];
  const f32x4 fz = {0.f, 0.f, 0.f, 0.f};
#pragma unroll
  for (int i = 0; i < MI; i++)
#pragma unroll
    for (int j = 0; j < 4; j++) acc[i][j] = fz;

  const int srow = tid >> 2;
  const int kq = (tid & 3) * 8;

  for (int kt = 0; kt < K; kt += 32) {
    gl2lds16(A + (size_t)(m0 + srow) * K + kt + kq, &As[tid * 8]);
    gl2lds16(A + (size_t)(m0 + 64 + srow) * K + kt + kq, &As[2048 + tid * 8]);
    gl2lds16(B + (size_t)(n0 + srow) * K + kt + kq, &Bs[tid * 8]);
    if (BN == 128)
      gl2lds16(B + (size_t)(n0 + 64 + srow) * K + kt + kq, &Bs[2048 + tid * 8]);
    __syncthreads();
    half8 af[MI], bf[4];
#pragma unroll
    for (int mi = 0; mi < MI; mi++)
      af[mi] = *(const half8*)&As[(mbase + mi * 16 + l16) * 32 + quad * 8];
#pragma unroll
    for (int ni = 0; ni < 4; ni++)
      bf[ni] = *(const half8*)&Bs[(nbase + ni * 16 + l16) * 32 + quad * 8];
#pragma unroll
    for (int mi = 0; mi < MI; mi++)
#pragma unroll
      for (int ni = 0; ni < 4; ni++)
        acc[mi][ni] = __builtin_amdgcn_mfma_f32_16x16x32_f16(af[mi], bf[ni], acc[mi][ni], 0, 0, 0);
    __syncthreads();
  }

#pragma unroll
  for (int mi = 0; mi < MI; mi++)
#pragma unroll
    for (int ni = 0; ni < 4; ni++)
#pragma unroll
      for (int r = 0; r < 4; r++) {
        int row = m0 + mbase + mi * 16 + quad * 4 + r;
        int col = n0 + nbase + ni * 16 + l16;
        float v = acc[mi][ni][r];
        if (MODE == 0) {
          Cf[(size_t)row * N + col] = v;
        } else {
          int which = col >> 10, h = (col >> 6) & 15, d = col & 63;
          int b = row >> 11, s = row & 2047;
          if (which == 0) v *= 0.125f;  // fold softmax scale into Q
          Ch[((((size_t)(which * 2 + b) * 16 + h) * 2048) + s) * 64 + d] = (_Float16)v;
        }
      }
}

// ---------------- fused causal attention ----------------
// Swapped-operand QK^T (lane owns one q row), K+V dbuf via gl2lds.
// R6 -> R7 changes (attn only):
//  (1) DEFERRED w export: tile kt's Ps stripe is exported at the TOP of
//      iteration kt+1 (post-barrier). The nt stores then have a full tile of
//      QK^T+PV to retire before the next barrier's implicit vmcnt(0), instead
//      of stalling every barrier on an HBM store round-trip.
//  (2) s_setprio(1) around the MFMA clusters (T5): 3 blocks/CU at different
//      kt phases = wave role diversity (m191 regime, +4-7%).
__global__ __launch_bounds__(256) void attn_kernel(const _Float16* __restrict__ qkv,
                                                   const _Float16* __restrict__ vt,
                                                   float* __restrict__ w_out,
                                                   _Float16* __restrict__ o_buf) {
  const int qt = 31 - blockIdx.x;  // heavy blocks launch first
  const int bh = blockIdx.y;
  const int tid = threadIdx.x;
  const int lane = tid & 63;
  const int wid = tid >> 6;
  const int quad = lane >> 4;
  const int l16 = lane & 15;

  const _Float16* qp = qkv + (size_t)bh * 131072;
  const _Float16* kp = qp + 4194304;
  const _Float16* vtb = vt + (size_t)bh * 131072;

  __shared__ __align__(16) _Float16 Ks[2][4096];  // [buf][chunk d0/d1][s][32]
  __shared__ __align__(16) _Float16 Vs[2][4096];  // [buf][chunk s0/s1][d][32]
  __shared__ __align__(16) _Float16 Ps[64][72];   // wave-private stripes

  const int qrow = qt * 64 + wid * 16 + l16;
  const half8 qa0 = *(const half8*)(qp + qrow * 64 + quad * 8);
  const half8 qa1 = *(const half8*)(qp + qrow * 64 + 32 + quad * 8);

  const int srow = tid >> 2;        // 0..63
  const int blk8 = (tid & 3) * 8;
  const f32x4 fz = {0.f, 0.f, 0.f, 0.f};
  const int qloc = wid * 16 + l16;  // this lane's q row within the 64-row tile
  const int kbase = quad * 4;       // this lane's k sub-offset within a 16-col block

  float* wbase = w_out + (size_t)bh * 4194304 + (size_t)qt * 131072;

  // ---- zerofill above-diagonal: nt streaming stores ----
  {
    const int rr = tid >> 4, cc = (tid & 15) * 4;
    for (int kt = qt + 1; kt < 32; kt++) {
      float* wz = wbase + (size_t)kt * 64 + cc;
#pragma unroll
      for (int p = 0; p < 4; p++)
        nt_store4(wz + (size_t)(p * 16 + rr) * 2048, fz);
    }
  }

  float lsum = 0.f;

  // ---- pass 1: row sums of exp(s); K staged via gl2lds, 2-deep ----
  int cur = 0;
  gl2lds16(kp + (size_t)srow * 64 + blk8, &Ks[0][tid * 8]);
  gl2lds16(kp + (size_t)srow * 64 + 32 + blk8, &Ks[0][2048 + tid * 8]);
  __syncthreads();
  for (int kt = 0; kt <= qt; kt++) {
    if (kt < qt) {
      gl2lds16(kp + (size_t)((kt + 1) * 64 + srow) * 64 + blk8, &Ks[cur ^ 1][tid * 8]);
      gl2lds16(kp + (size_t)((kt + 1) * 64 + srow) * 64 + 32 + blk8, &Ks[cur ^ 1][2048 + tid * 8]);
    }
    f32x4 sacc[4];
    __builtin_amdgcn_s_setprio(1);
#pragma unroll
    for (int ni = 0; ni < 4; ni++) {
      half8 kb0 = *(const half8*)&Ks[cur][(ni * 16 + l16) * 32 + quad * 8];
      half8 kb1 = *(const half8*)&Ks[cur][2048 + (ni * 16 + l16) * 32 + quad * 8];
      f32x4 s = fz;
      s = __builtin_amdgcn_mfma_f32_16x16x32_f16(kb0, qa0, s, 0, 0, 0);  // swapped: S^T
      s = __builtin_amdgcn_mfma_f32_16x16x32_f16(kb1, qa1, s, 0, 0, 0);
      sacc[ni] = s;
    }
    __builtin_amdgcn_s_setprio(0);
    if (kt < qt) {
#pragma unroll
      for (int ni = 0; ni < 4; ni++)
#pragma unroll
        for (int r = 0; r < 4; r++) lsum += __expf(sacc[ni][r]);
    } else {  // diagonal tile: include only k <= q
#pragma unroll
      for (int ni = 0; ni < 4; ni++)
#pragma unroll
        for (int r = 0; r < 4; r++) {
          if (ni * 16 + kbase + r <= qloc) lsum += __expf(sacc[ni][r]);
        }
    }
    __syncthreads();
    cur ^= 1;
  }
  // reduce over the 4 quads holding the same q row
  lsum += __shfl_xor(lsum, 16);
  lsum += __shfl_xor(lsum, 32);
  const float invl = 1.0f / lsum;

  f32x4 oacc[4];
#pragma unroll
  for (int di = 0; di < 4; di++) oacc[di] = fz;

  // ---- pass 2: recompute S^T, P -> Ps, PV; w export deferred one tile ----
  cur = 0;
  gl2lds16(kp + (size_t)srow * 64 + blk8, &Ks[0][tid * 8]);
  gl2lds16(kp + (size_t)srow * 64 + 32 + blk8, &Ks[0][2048 + tid * 8]);
  gl2lds16(vtb + (size_t)srow * 2048 + blk8, &Vs[0][tid * 8]);
  gl2lds16(vtb + (size_t)srow * 2048 + 32 + blk8, &Vs[0][2048 + tid * 8]);
  __syncthreads();
  for (int kt = 0; kt <= qt; kt++) {
    // (1) deferred export of tile kt-1: Ps stripe is wave-private and still
    // intact; stores issued here retire during this tile's compute.
    if (kt > 0) {
      const int erow = lane >> 2;
      const int ec = (lane & 3) * 4;
      const _Float16* prow = &Ps[wid * 16 + erow][0];
      float* wrow = wbase + (size_t)(wid * 16 + erow) * 2048 + (kt - 1) * 64;
#pragma unroll
      for (int j = 0; j < 4; j++) {
        half4 h = *(const half4*)(prow + j * 16 + ec);
        f32x4 o;
        o[0] = (float)h[0]; o[1] = (float)h[1]; o[2] = (float)h[2]; o[3] = (float)h[3];
        nt_store4(wrow + j * 16 + ec, o);
      }
    }
    if (kt < qt) {
      const int kn = kt + 1;
      gl2lds16(kp + (size_t)(kn * 64 + srow) * 64 + blk8, &Ks[cur ^ 1][tid * 8]);
      gl2lds16(kp + (size_t)(kn * 64 + srow) * 64 + 32 + blk8, &Ks[cur ^ 1][2048 + tid * 8]);
      gl2lds16(vtb + (size_t)srow * 2048 + kn * 64 + blk8, &Vs[cur ^ 1][tid * 8]);
      gl2lds16(vtb + (size_t)srow * 2048 + kn * 64 + 32 + blk8, &Vs[cur ^ 1][2048 + tid * 8]);
    }
    f32x4 sacc[4];
    __builtin_amdgcn_s_setprio(1);
#pragma unroll
    for (int ni = 0; ni < 4; ni++) {
      half8 kb0 = *(const half8*)&Ks[cur][(ni * 16 + l16) * 32 + quad * 8];
      half8 kb1 = *(const half8*)&Ks[cur][2048 + (ni * 16 + l16) * 32 + quad * 8];
      f32x4 s = fz;
      s = __builtin_amdgcn_mfma_f32_16x16x32_f16(kb0, qa0, s, 0, 0, 0);  // swapped: S^T
      s = __builtin_amdgcn_mfma_f32_16x16x32_f16(kb1, qa1, s, 0, 0, 0);
      sacc[ni] = s;
    }
    __builtin_amdgcn_s_setprio(0);
    const bool diag = (kt == qt);
#pragma unroll
    for (int ni = 0; ni < 4; ni++) {
      half4 ph;
#pragma unroll
      for (int r = 0; r < 4; r++) {
        float p = __expf(sacc[ni][r]) * invl;
        if (diag && (ni * 16 + kbase + r > qloc)) p = 0.0f;
        ph[r] = (_Float16)p;
      }
      *(half4*)&Ps[qloc][ni * 16 + kbase] = ph;  // wave-private row, packed write
    }
    // PV: A-frag from Ps (own stripe), B-frag from Vs
    __builtin_amdgcn_s_setprio(1);
#pragma unroll
    for (int kk = 0; kk < 2; kk++) {
      half8 pa = *(const half8*)&Ps[wid * 16 + l16][kk * 32 + quad * 8];
#pragma unroll
      for (int di = 0; di < 4; di++) {
        half8 vb = *(const half8*)&Vs[cur][kk * 2048 + (di * 16 + l16) * 32 + quad * 8];
        oacc[di] = __builtin_amdgcn_mfma_f32_16x16x32_f16(pa, vb, oacc[di], 0, 0, 0);
      }
    }
    __builtin_amdgcn_s_setprio(0);
    __syncthreads();
    cur ^= 1;
  }
  // final export: tile qt
  {
    const int erow = lane >> 2;
    const int ec = (lane & 3) * 4;
    const _Float16* prow = &Ps[wid * 16 + erow][0];
    float* wrow = wbase + (size_t)(wid * 16 + erow) * 2048 + (size_t)qt * 64;
#pragma unroll
    for (int j = 0; j < 4; j++) {
      half4 h = *(const half4*)(prow + j * 16 + ec);
      f32x4 o;
      o[0] = (float)h[0]; o[1] = (float)h[1]; o[2] = (float)h[2]; o[3] = (float)h[3];
      nt_store4(wrow + j * 16 + ec, o);
    }
  }

  const int b = bh >> 4, h = bh & 15;
#pragma unroll
  for (int di = 0; di < 4; di++)
#pragma unroll
    for (int r = 0; r < 4; r++) {
      int s = qt * 64 + wid * 16 + quad * 4 + r;
      int d = di * 16 + l16;
      o_buf[((size_t)(b * 2048 + s) * 16 + h) * 64 + d] = (_Float16)oacc[di][r];
    }
}

extern "C" void kernel_launch(void* const* d_in, const int* in_sizes, int n_in,
                              void* d_out, int out_size, void* d_ws, size_t ws_size,
                              hipStream_t stream) {
  const float* x = (const float*)d_in[0];
  const float* w_qkv = (const float*)d_in[1];
  const float* w_proj = (const float*)d_in[2];
  float* out = (float*)d_out;
  float* w_attn = out + (size_t)4194304;

  // ws (bytes): x16 0..8M | wqkvT 8..14M | wprojT 14..16M | qkv 16..40M |
  //             vT 40..48M | o 48..56M
  char* ws = (char*)d_ws;
  _Float16* x16 = (_Float16*)ws;
  _Float16* wqkvT = (_Float16*)(ws + (size_t)(8 << 20));
  _Float16* wprojT = (_Float16*)(ws + (size_t)(14 << 20));
  _Float16* qkvb = (_Float16*)(ws + (size_t)(16 << 20));
  _Float16* vT = (_Float16*)(ws + (size_t)(40 << 20));
  _Float16* ob = (_Float16*)(ws + (size_t)(48 << 20));

  cvt_kernel<<<2048, 256, 0, stream>>>(x, x16, 4194304);
  cvtT_kernel<<<dim3(48, 16), 256, 0, stream>>>(w_qkv, wqkvT, 1024, 3072);
  cvtT_kernel<<<dim3(16, 16), 256, 0, stream>>>(w_proj, wprojT, 1024, 1024);

  gemm16<1, 128><<<dim3(24, 32), 256, 0, stream>>>(x16, wqkvT, nullptr, qkvb, 4096, 3072, 1024);
  vtrans_kernel<<<dim3(32, 32), 256, 0, stream>>>(qkvb + (size_t)2 * 4194304, vT);
  attn_kernel<<<dim3(32, 32), 256, 0, stream>>>(qkvb, vT, w_attn, ob);
  gemm16<0, 64><<<dim3(16, 32), 256, 0, stream>>>(ob, wprojT, out, nullptr, 4096, 1024, 1024);
}

// Round 8
// 687.488 us; speedup vs baseline: 1.2936x; 1.0097x over previous
//
#include <hip/hip_runtime.h>

typedef _Float16 half8 __attribute__((ext_vector_type(8)));
typedef _Float16 half4 __attribute__((ext_vector_type(4)));
typedef float f32x4 __attribute__((ext_vector_type(4)));

// async global->LDS 16B: LDS dest must be wave-uniform base + lane*16.
__device__ __forceinline__ void gl2lds16(const _Float16* g, _Float16* l) {
  __builtin_amdgcn_global_load_lds((const __attribute__((address_space(1))) void*)g,
                                   (__attribute__((address_space(3))) void*)l, 16, 0, 0);
}

__device__ __forceinline__ void nt_store4(float* p, f32x4 v) {
  __builtin_nontemporal_store(v, (f32x4*)p);
}

// Ps bank-conflict swizzle: XOR col (halves) by (row&7)*8. Keeps 16B groups
// contiguous; spreads the 128B row stride across 8 bank groups (2-way max).
#define PSW(row, col) ((col) ^ (((row) & 7) << 3))

// ---------------- fp32 -> fp16 convert ----------------
__global__ __launch_bounds__(256) void cvt_kernel(const float* __restrict__ in,
                                                  _Float16* __restrict__ out, int n) {
  int i = (blockIdx.x * 256 + threadIdx.x) * 8;
  if (i >= n) return;
  float4 a = *(const float4*)(in + i);
  float4 b = *(const float4*)(in + i + 4);
  half8 o;
  o[0] = (_Float16)a.x; o[1] = (_Float16)a.y; o[2] = (_Float16)a.z; o[3] = (_Float16)a.w;
  o[4] = (_Float16)b.x; o[5] = (_Float16)b.y; o[6] = (_Float16)b.z; o[7] = (_Float16)b.w;
  *(half8*)(out + i) = o;
}

// ---------- fp32 [K][N] -> fp16 [N][K] transpose+convert, 64x64 tiles ----------
__global__ __launch_bounds__(256) void cvtT_kernel(const float* __restrict__ in,
                                                   _Float16* __restrict__ out,
                                                   int K, int N) {
  __shared__ float Ts[64][65];
  const int k0 = blockIdx.y * 64, n0 = blockIdx.x * 64;
  const int t = threadIdx.x;
  const int r = t >> 4, c = (t & 15) * 4;
#pragma unroll
  for (int i = 0; i < 4; i++) {
    float4 v = *(const float4*)(in + (size_t)(k0 + r + i * 16) * N + n0 + c);
    Ts[r + i * 16][c] = v.x; Ts[r + i * 16][c + 1] = v.y;
    Ts[r + i * 16][c + 2] = v.z; Ts[r + i * 16][c + 3] = v.w;
  }
  __syncthreads();
  const int nl = t >> 2, kq = (t & 3) * 16;
  half8 o0, o1;
#pragma unroll
  for (int j = 0; j < 8; j++) {
    o0[j] = (_Float16)Ts[kq + j][nl];
    o1[j] = (_Float16)Ts[kq + 8 + j][nl];
  }
  *(half8*)(out + (size_t)(n0 + nl) * K + k0 + kq) = o0;
  *(half8*)(out + (size_t)(n0 + nl) * K + k0 + kq + 8) = o1;
}

// ---------- V [bh][s][64] -> V^T [bh][64][s] fp16 transpose, 64x64 tiles ----------
__global__ __launch_bounds__(256) void vtrans_kernel(const _Float16* __restrict__ v,
                                                     _Float16* __restrict__ vt) {
  __shared__ _Float16 Ht[64][72];
  const int s0 = blockIdx.x * 64;
  const _Float16* vb = v + (size_t)blockIdx.y * 131072;
  _Float16* vtb = vt + (size_t)blockIdx.y * 131072;
  const int t = threadIdx.x;
  const int sl = t >> 3, dq = (t & 7) * 8;
  *(half8*)&Ht[sl][dq] = *(const half8*)(vb + (s0 + sl) * 64 + dq);
  *(half8*)&Ht[sl + 32][dq] = *(const half8*)(vb + (s0 + sl + 32) * 64 + dq);
  __syncthreads();
  const int dl = t >> 2, sq = (t & 3) * 16;
  half8 o0, o1;
#pragma unroll
  for (int j = 0; j < 8; j++) {
    o0[j] = Ht[sq + j][dl];
    o1[j] = Ht[sq + 8 + j][dl];
  }
  *(half8*)(vtb + (size_t)dl * 2048 + s0 + sq) = o0;
  *(half8*)(vtb + (size_t)dl * 2048 + s0 + sq + 8) = o1;
}

// ---------------- m97-style f16 MFMA GEMM, B pre-transposed [N][K] ----------------
// MODE 1 epilogue pre-scales Q (which==0) by 0.125 = 1/sqrt(64), exact pow2.
template <int MODE, int BN>
__global__ __launch_bounds__(256) void gemm16(const _Float16* __restrict__ A,
                                              const _Float16* __restrict__ B,
                                              float* __restrict__ Cf,
                                              _Float16* __restrict__ Ch,
                                              int M, int N, int K) {
  constexpr int MI = (BN == 128) ? 4 : 2;
  __shared__ __align__(16) _Float16 As[128 * 32];
  __shared__ __align__(16) _Float16 Bs[BN * 32];
  const int tid = threadIdx.x;
  const int lane = tid & 63;
  const int wid = tid >> 6;
  const int quad = lane >> 4;
  const int l16 = lane & 15;
  const int mbase = (BN == 128) ? (wid >> 1) * 64 : wid * 32;
  const int nbase = (BN == 128) ? (wid & 1) * 64 : 0;
  const int m0 = blockIdx.y * 128;
  const int n0 = blockIdx.x * BN;

  f32x4 acc[MI][4];
  const f32x4 fz = {0.f, 0.f, 0.f, 0.f};
#pragma unroll
  for (int i = 0; i < MI; i++)
#pragma unroll
    for (int j = 0; j < 4; j++) acc[i][j] = fz;

  const int srow = tid >> 2;
  const int kq = (tid & 3) * 8;

  for (int kt = 0; kt < K; kt += 32) {
    gl2lds16(A + (size_t)(m0 + srow) * K + kt + kq, &As[tid * 8]);
    gl2lds16(A + (size_t)(m0 + 64 + srow) * K + kt + kq, &As[2048 + tid * 8]);
    gl2lds16(B + (size_t)(n0 + srow) * K + kt + kq, &Bs[tid * 8]);
    if (BN == 128)
      gl2lds16(B + (size_t)(n0 + 64 + srow) * K + kt + kq, &Bs[2048 + tid * 8]);
    __syncthreads();
    half8 af[MI], bf[4];
#pragma unroll
    for (int mi = 0; mi < MI; mi++)
      af[mi] = *(const half8*)&As[(mbase + mi * 16 + l16) * 32 + quad * 8];
#pragma unroll
    for (int ni = 0; ni < 4; ni++)
      bf[ni] = *(const half8*)&Bs[(nbase + ni * 16 + l16) * 32 + quad * 8];
#pragma unroll
    for (int mi = 0; mi < MI; mi++)
#pragma unroll
      for (int ni = 0; ni < 4; ni++)
        acc[mi][ni] = __builtin_amdgcn_mfma_f32_16x16x32_f16(af[mi], bf[ni], acc[mi][ni], 0, 0, 0);
    __syncthreads();
  }

#pragma unroll
  for (int mi = 0; mi < MI; mi++)
#pragma unroll
    for (int ni = 0; ni < 4; ni++)
#pragma unroll
      for (int r = 0; r < 4; r++) {
        int row = m0 + mbase + mi * 16 + quad * 4 + r;
        int col = n0 + nbase + ni * 16 + l16;
        float v = acc[mi][ni][r];
        if (MODE == 0) {
          Cf[(size_t)row * N + col] = v;
        } else {
          int which = col >> 10, h = (col >> 6) & 15, d = col & 63;
          int b = row >> 11, s = row & 2047;
          if (which == 0) v *= 0.125f;  // fold softmax scale into Q
          Ch[((((size_t)(which * 2 + b) * 16 + h) * 2048) + s) * 64 + d] = (_Float16)v;
        }
      }
}

// ---------------- fused causal attention ----------------
// Swapped-operand QK^T (lane owns one q row), K+V dbuf via gl2lds, deferred
// w export, setprio around MFMA. R7 -> R8 (single variable):
//   Ps padding (+8/row) replaced by XOR swizzle PSW -> LDS 41984 -> 40960 B
//   = exactly 4 blocks/CU (was 3). Occupancy 12 -> 16 waves/CU to hide the
//   per-tile staging/barrier stalls. Numerics identical.
__global__ __launch_bounds__(256) void attn_kernel(const _Float16* __restrict__ qkv,
                                                   const _Float16* __restrict__ vt,
                                                   float* __restrict__ w_out,
                                                   _Float16* __restrict__ o_buf) {
  const int qt = 31 - blockIdx.x;  // heavy blocks launch first
  const int bh = blockIdx.y;
  const int tid = threadIdx.x;
  const int lane = tid & 63;
  const int wid = tid >> 6;
  const int quad = lane >> 4;
  const int l16 = lane & 15;

  const _Float16* qp = qkv + (size_t)bh * 131072;
  const _Float16* kp = qp + 4194304;
  const _Float16* vtb = vt + (size_t)bh * 131072;

  __shared__ __align__(16) _Float16 Ks[2][4096];  // [buf][chunk d0/d1][s][32]
  __shared__ __align__(16) _Float16 Vs[2][4096];  // [buf][chunk s0/s1][d][32]
  __shared__ __align__(16) _Float16 Ps[64][64];   // XOR-swizzled, wave-private rows

  const int qrow = qt * 64 + wid * 16 + l16;
  const half8 qa0 = *(const half8*)(qp + qrow * 64 + quad * 8);
  const half8 qa1 = *(const half8*)(qp + qrow * 64 + 32 + quad * 8);

  const int srow = tid >> 2;        // 0..63
  const int blk8 = (tid & 3) * 8;
  const f32x4 fz = {0.f, 0.f, 0.f, 0.f};
  const int qloc = wid * 16 + l16;  // this lane's q row within the 64-row tile
  const int kbase = quad * 4;       // this lane's k sub-offset within a 16-col block

  float* wbase = w_out + (size_t)bh * 4194304 + (size_t)qt * 131072;

  // ---- zerofill above-diagonal: nt streaming stores ----
  {
    const int rr = tid >> 4, cc = (tid & 15) * 4;
    for (int kt = qt + 1; kt < 32; kt++) {
      float* wz = wbase + (size_t)kt * 64 + cc;
#pragma unroll
      for (int p = 0; p < 4; p++)
        nt_store4(wz + (size_t)(p * 16 + rr) * 2048, fz);
    }
  }

  float lsum = 0.f;

  // ---- pass 1: row sums of exp(s); K staged via gl2lds, 2-deep ----
  int cur = 0;
  gl2lds16(kp + (size_t)srow * 64 + blk8, &Ks[0][tid * 8]);
  gl2lds16(kp + (size_t)srow * 64 + 32 + blk8, &Ks[0][2048 + tid * 8]);
  __syncthreads();
  for (int kt = 0; kt <= qt; kt++) {
    if (kt < qt) {
      gl2lds16(kp + (size_t)((kt + 1) * 64 + srow) * 64 + blk8, &Ks[cur ^ 1][tid * 8]);
      gl2lds16(kp + (size_t)((kt + 1) * 64 + srow) * 64 + 32 + blk8, &Ks[cur ^ 1][2048 + tid * 8]);
    }
    f32x4 sacc[4];
    __builtin_amdgcn_s_setprio(1);
#pragma unroll
    for (int ni = 0; ni < 4; ni++) {
      half8 kb0 = *(const half8*)&Ks[cur][(ni * 16 + l16) * 32 + quad * 8];
      half8 kb1 = *(const half8*)&Ks[cur][2048 + (ni * 16 + l16) * 32 + quad * 8];
      f32x4 s = fz;
      s = __builtin_amdgcn_mfma_f32_16x16x32_f16(kb0, qa0, s, 0, 0, 0);  // swapped: S^T
      s = __builtin_amdgcn_mfma_f32_16x16x32_f16(kb1, qa1, s, 0, 0, 0);
      sacc[ni] = s;
    }
    __builtin_amdgcn_s_setprio(0);
    if (kt < qt) {
#pragma unroll
      for (int ni = 0; ni < 4; ni++)
#pragma unroll
        for (int r = 0; r < 4; r++) lsum += __expf(sacc[ni][r]);
    } else {  // diagonal tile: include only k <= q
#pragma unroll
      for (int ni = 0; ni < 4; ni++)
#pragma unroll
        for (int r = 0; r < 4; r++) {
          if (ni * 16 + kbase + r <= qloc) lsum += __expf(sacc[ni][r]);
        }
    }
    __syncthreads();
    cur ^= 1;
  }
  // reduce over the 4 quads holding the same q row
  lsum += __shfl_xor(lsum, 16);
  lsum += __shfl_xor(lsum, 32);
  const float invl = 1.0f / lsum;

  f32x4 oacc[4];
#pragma unroll
  for (int di = 0; di < 4; di++) oacc[di] = fz;

  // ---- pass 2: recompute S^T, P -> Ps, PV; w export deferred one tile ----
  cur = 0;
  gl2lds16(kp + (size_t)srow * 64 + blk8, &Ks[0][tid * 8]);
  gl2lds16(kp + (size_t)srow * 64 + 32 + blk8, &Ks[0][2048 + tid * 8]);
  gl2lds16(vtb + (size_t)srow * 2048 + blk8, &Vs[0][tid * 8]);
  gl2lds16(vtb + (size_t)srow * 2048 + 32 + blk8, &Vs[0][2048 + tid * 8]);
  __syncthreads();
  for (int kt = 0; kt <= qt; kt++) {
    // deferred export of tile kt-1: Ps stripe is wave-private and still intact;
    // stores issued here retire during this tile's compute.
    if (kt > 0) {
      const int erow = lane >> 2;
      const int ec = (lane & 3) * 4;
      const _Float16* prow = &Ps[wid * 16 + erow][0];
      float* wrow = wbase + (size_t)(wid * 16 + erow) * 2048 + (kt - 1) * 64;
#pragma unroll
      for (int j = 0; j < 4; j++) {
        half4 h = *(const half4*)(prow + PSW(erow, j * 16 + ec));
        f32x4 o;
        o[0] = (float)h[0]; o[1] = (float)h[1]; o[2] = (float)h[2]; o[3] = (float)h[3];
        nt_store4(wrow + j * 16 + ec, o);
      }
    }
    if (kt < qt) {
      const int kn = kt + 1;
      gl2lds16(kp + (size_t)(kn * 64 + srow) * 64 + blk8, &Ks[cur ^ 1][tid * 8]);
      gl2lds16(kp + (size_t)(kn * 64 + srow) * 64 + 32 + blk8, &Ks[cur ^ 1][2048 + tid * 8]);
      gl2lds16(vtb + (size_t)srow * 2048 + kn * 64 + blk8, &Vs[cur ^ 1][tid * 8]);
      gl2lds16(vtb + (size_t)srow * 2048 + kn * 64 + 32 + blk8, &Vs[cur ^ 1][2048 + tid * 8]);
    }
    f32x4 sacc[4];
    __builtin_amdgcn_s_setprio(1);
#pragma unroll
    for (int ni = 0; ni < 4; ni++) {
      half8 kb0 = *(const half8*)&Ks[cur][(ni * 16 + l16) * 32 + quad * 8];
      half8 kb1 = *(const half8*)&Ks[cur][2048 + (ni * 16 + l16) * 32 + quad * 8];
      f32x4 s = fz;
      s = __builtin_amdgcn_mfma_f32_16x16x32_f16(kb0, qa0, s, 0, 0, 0);  // swapped: S^T
      s = __builtin_amdgcn_mfma_f32_16x16x32_f16(kb1, qa1, s, 0, 0, 0);
      sacc[ni] = s;
    }
    __builtin_amdgcn_s_setprio(0);
    const bool diag = (kt == qt);
#pragma unroll
    for (int ni = 0; ni < 4; ni++) {
      half4 ph;
#pragma unroll
      for (int r = 0; r < 4; r++) {
        float p = __expf(sacc[ni][r]) * invl;
        if (diag && (ni * 16 + kbase + r > qloc)) p = 0.0f;
        ph[r] = (_Float16)p;
      }
      *(half4*)&Ps[qloc][PSW(qloc, ni * 16 + kbase)] = ph;  // wave-private row
    }
    // PV: A-frag from Ps (own stripe), B-frag from Vs
    __builtin_amdgcn_s_setprio(1);
#pragma unroll
    for (int kk = 0; kk < 2; kk++) {
      half8 pa = *(const half8*)&Ps[wid * 16 + l16][PSW(l16, kk * 32 + quad * 8)];
#pragma unroll
      for (int di = 0; di < 4; di++) {
        half8 vb = *(const half8*)&Vs[cur][kk * 2048 + (di * 16 + l16) * 32 + quad * 8];
        oacc[di] = __builtin_amdgcn_mfma_f32_16x16x32_f16(pa, vb, oacc[di], 0, 0, 0);
      }
    }
    __builtin_amdgcn_s_setprio(0);
    __syncthreads();
    cur ^= 1;
  }
  // final export: tile qt
  {
    const int erow = lane >> 2;
    const int ec = (lane & 3) * 4;
    const _Float16* prow = &Ps[wid * 16 + erow][0];
    float* wrow = wbase + (size_t)(wid * 16 + erow) * 2048 + (size_t)qt * 64;
#pragma unroll
    for (int j = 0; j < 4; j++) {
      half4 h = *(const half4*)(prow + PSW(erow, j * 16 + ec));
      f32x4 o;
      o[0] = (float)h[0]; o[1] = (float)h[1]; o[2] = (float)h[2]; o[3] = (float)h[3];
      nt_store4(wrow + j * 16 + ec, o);
    }
  }

  const int b = bh >> 4, h = bh & 15;
#pragma unroll
  for (int di = 0; di < 4; di++)
#pragma unroll
    for (int r = 0; r < 4; r++) {
      int s = qt * 64 + wid * 16 + quad * 4 + r;
      int d = di * 16 + l16;
      o_buf[((size_t)(b * 2048 + s) * 16 + h) * 64 + d] = (_Float16)oacc[di][r];
    }
}

extern "C" void kernel_launch(void* const* d_in, const int* in_sizes, int n_in,
                              void* d_out, int out_size, void* d_ws, size_t ws_size,
                              hipStream_t stream) {
  const float* x = (const float*)d_in[0];
  const float* w_qkv = (const float*)d_in[1];
  const float* w_proj = (const float*)d_in[2];
  float* out = (float*)d_out;
  float* w_attn = out + (size_t)4194304;

  // ws (bytes): x16 0..8M | wqkvT 8..14M | wprojT 14..16M | qkv 16..40M |
  //             vT 40..48M | o 48..56M
  char* ws = (char*)d_ws;
  _Float16* x16 = (_Float16*)ws;
  _Float16* wqkvT = (_Float16*)(ws + (size_t)(8 << 20));
  _Float16* wprojT = (_Float16*)(ws + (size_t)(14 << 20));
  _Float16* qkvb = (_Float16*)(ws + (size_t)(16 << 20));
  _Float16* vT = (_Float16*)(ws + (size_t)(40 << 20));
  _Float16* ob = (_Float16*)(ws + (size_t)(48 << 20));

  cvt_kernel<<<2048, 256, 0, stream>>>(x, x16, 4194304);
  cvtT_kernel<<<dim3(48, 16), 256, 0, stream>>>(w_qkv, wqkvT, 1024, 3072);
  cvtT_kernel<<<dim3(16, 16), 256, 0, stream>>>(w_proj, wprojT, 1024, 1024);

  gemm16<1, 128><<<dim3(24, 32), 256, 0, stream>>>(x16, wqkvT, nullptr, qkvb, 4096, 3072, 1024);
  vtrans_kernel<<<dim3(32, 32), 256, 0, stream>>>(qkvb + (size_t)2 * 4194304, vT);
  attn_kernel<<<dim3(32, 32), 256, 0, stream>>>(qkvb, vT, w_attn, ob);
  gemm16<0, 64><<<dim3(16, 32), 256, 0, stream>>>(ob, wprojT, out, nullptr, 4096, 1024, 1024);
}

// Round 9
// 683.159 us; speedup vs baseline: 1.3018x; 1.0063x over previous
//
#include <hip/hip_runtime.h>

typedef _Float16 half8 __attribute__((ext_vector_type(8)));
typedef _Float16 half4 __attribute__((ext_vector_type(4)));
typedef float f32x4 __attribute__((ext_vector_type(4)));

// async global->LDS 16B: LDS dest must be wave-uniform base + lane*16.
__device__ __forceinline__ void gl2lds16(const _Float16* g, _Float16* l) {
  __builtin_amdgcn_global_load_lds((const __attribute__((address_space(1))) void*)g,
                                   (__attribute__((address_space(3))) void*)l, 16, 0, 0);
}

__device__ __forceinline__ void nt_store4(float* p, f32x4 v) {
  __builtin_nontemporal_store(v, (f32x4*)p);
}

// Ps bank-conflict swizzle (attn): XOR col (halves) by (row&7)*8.
#define PSW(row, col) ((col) ^ (((row) & 7) << 3))

// ---------------- fp32 -> fp16 convert ----------------
__global__ __launch_bounds__(256) void cvt_kernel(const float* __restrict__ in,
                                                  _Float16* __restrict__ out, int n) {
  int i = (blockIdx.x * 256 + threadIdx.x) * 8;
  if (i >= n) return;
  float4 a = *(const float4*)(in + i);
  float4 b = *(const float4*)(in + i + 4);
  half8 o;
  o[0] = (_Float16)a.x; o[1] = (_Float16)a.y; o[2] = (_Float16)a.z; o[3] = (_Float16)a.w;
  o[4] = (_Float16)b.x; o[5] = (_Float16)b.y; o[6] = (_Float16)b.z; o[7] = (_Float16)b.w;
  *(half8*)(out + i) = o;
}

// ---------- fp32 [K][N] -> fp16 [N][K] transpose+convert, 64x64 tiles ----------
__global__ __launch_bounds__(256) void cvtT_kernel(const float* __restrict__ in,
                                                   _Float16* __restrict__ out,
                                                   int K, int N) {
  __shared__ float Ts[64][65];
  const int k0 = blockIdx.y * 64, n0 = blockIdx.x * 64;
  const int t = threadIdx.x;
  const int r = t >> 4, c = (t & 15) * 4;
#pragma unroll
  for (int i = 0; i < 4; i++) {
    float4 v = *(const float4*)(in + (size_t)(k0 + r + i * 16) * N + n0 + c);
    Ts[r + i * 16][c] = v.x; Ts[r + i * 16][c + 1] = v.y;
    Ts[r + i * 16][c + 2] = v.z; Ts[r + i * 16][c + 3] = v.w;
  }
  __syncthreads();
  const int nl = t >> 2, kq = (t & 3) * 16;
  half8 o0, o1;
#pragma unroll
  for (int j = 0; j < 8; j++) {
    o0[j] = (_Float16)Ts[kq + j][nl];
    o1[j] = (_Float16)Ts[kq + 8 + j][nl];
  }
  *(half8*)(out + (size_t)(n0 + nl) * K + k0 + kq) = o0;
  *(half8*)(out + (size_t)(n0 + nl) * K + k0 + kq + 8) = o1;
}

// ---------- V [bh][s][64] -> V^T [bh][64][s] fp16 transpose, 64x64 tiles ----------
__global__ __launch_bounds__(256) void vtrans_kernel(const _Float16* __restrict__ v,
                                                     _Float16* __restrict__ vt) {
  __shared__ _Float16 Ht[64][72];
  const int s0 = blockIdx.x * 64;
  const _Float16* vb = v + (size_t)blockIdx.y * 131072;
  _Float16* vtb = vt + (size_t)blockIdx.y * 131072;
  const int t = threadIdx.x;
  const int sl = t >> 3, dq = (t & 7) * 8;
  *(half8*)&Ht[sl][dq] = *(const half8*)(vb + (s0 + sl) * 64 + dq);
  *(half8*)&Ht[sl + 32][dq] = *(const half8*)(vb + (s0 + sl + 32) * 64 + dq);
  __syncthreads();
  const int dl = t >> 2, sq = (t & 3) * 16;
  half8 o0, o1;
#pragma unroll
  for (int j = 0; j < 8; j++) {
    o0[j] = Ht[sq + j][dl];
    o1[j] = Ht[sq + 8 + j][dl];
  }
  *(half8*)(vtb + (size_t)dl * 2048 + s0 + sq) = o0;
  *(half8*)(vtb + (size_t)dl * 2048 + s0 + sq + 8) = o1;
}

// ---------------- 256x256 counted-vmcnt f16 GEMM for QKV (T2+T4) ----------------
// BM=BN=256, BK=64, 512 thr = 8 waves (2m x 4n), per-wave C = 128x64.
// LDS: 2 bufs x (A 256x64 + B 256x64) fp16 = 128 KB; one K-tile per buffer
// = exactly 8 gl2lds/thread. Loop: barrierA -> issue STAGE(t+1) -> vmcnt(8)
// (oldest 8 = tile t's loads retired) -> barrierB -> compute tile t. vmcnt
// never 0 in main loop (T4). LDS XOR swizzle (row&7)<<3 halves, applied as
// inverse-swizzled global SOURCE + swizzled ds_read (rule 21; gl2lds dest
// stays linear). Epilogue: qkv scatter, Q pre-scaled by 0.125.
__global__ __launch_bounds__(512, 2) void gemmqkv(const _Float16* __restrict__ A,
                                                  const _Float16* __restrict__ B,
                                                  _Float16* __restrict__ Ch) {
  __shared__ __align__(16) _Float16 Abuf[2][256 * 64];
  __shared__ __align__(16) _Float16 Bbuf[2][256 * 64];
  const int tid = threadIdx.x;
  const int lane = tid & 63;
  const int wid = tid >> 6;          // 0..7
  const int quad = lane >> 4;
  const int l16 = lane & 15;
  const int wm = wid >> 2;           // 0..1
  const int wn = wid & 3;            // 0..3
  const int m0 = blockIdx.y * 256;
  const int n0 = blockIdx.x * 256;

  f32x4 acc[8][4];
  const f32x4 fz = {0.f, 0.f, 0.f, 0.f};
#pragma unroll
  for (int i = 0; i < 8; i++)
#pragma unroll
    for (int j = 0; j < 4; j++) acc[i][j] = fz;

  // stage source mapping: linear dest byte p -> (row, swizzle-inverted col)
  int srow[4], scol[4], sdst[4];
#pragma unroll
  for (int j = 0; j < 4; j++) {
    int p = (j * 512 + tid) * 16;     // linear dest byte in [0, 32768)
    int r = p >> 7;                   // row 0..255 (swizzle keeps row bits)
    int ch = ((p & 127) >> 1) ^ ((r & 7) << 3);  // logical col (halves)
    srow[j] = r;
    scol[j] = ch;
    sdst[j] = p >> 1;                 // dest half index (linear)
  }

#define STAGE(kt, s)                                                              \
  {                                                                               \
    const int k0_ = (kt) * 64;                                                    \
    _Float16* as_ = Abuf[s];                                                      \
    _Float16* bs_ = Bbuf[s];                                                      \
    _Pragma("unroll")                                                             \
    for (int j = 0; j < 4; j++)                                                   \
      gl2lds16(A + (size_t)(m0 + srow[j]) * 1024 + k0_ + scol[j], as_ + sdst[j]); \
    _Pragma("unroll")                                                             \
    for (int j = 0; j < 4; j++)                                                   \
      gl2lds16(B + (size_t)(n0 + srow[j]) * 1024 + k0_ + scol[j], bs_ + sdst[j]); \
  }

  STAGE(0, 0);
  for (int t = 0; t < 16; t++) {
    // barrier A: every wave finished reading buf[(t+1)&1] (iteration t-1)
    asm volatile("" ::: "memory");
    __builtin_amdgcn_s_barrier();
    asm volatile("" ::: "memory");
    if (t + 1 < 16) {
      STAGE(t + 1, (t + 1) & 1);
      asm volatile("s_waitcnt vmcnt(8)" ::: "memory");  // tile t's 8 loads retired
    } else {
      asm volatile("s_waitcnt vmcnt(0)" ::: "memory");
    }
    // barrier B: ALL threads' tile-t stages retired -> buf[t&1] valid
    __builtin_amdgcn_s_barrier();
    asm volatile("" ::: "memory");

    const _Float16* Ab = Abuf[t & 1];
    const _Float16* Bb = Bbuf[t & 1];
    half8 bf[2][4];
#pragma unroll
    for (int kk = 0; kk < 2; kk++)
#pragma unroll
      for (int ni = 0; ni < 4; ni++) {
        int r = wn * 64 + ni * 16 + l16;
        int c = kk * 32 + quad * 8;
        bf[kk][ni] = *(const half8*)(Bb + r * 64 + (c ^ ((r & 7) << 3)));
      }
#pragma unroll
    for (int mi = 0; mi < 8; mi++) {
      int r = wm * 128 + mi * 16 + l16;
      half8 a0 = *(const half8*)(Ab + r * 64 + ((quad * 8) ^ ((r & 7) << 3)));
      half8 a1 = *(const half8*)(Ab + r * 64 + ((32 + quad * 8) ^ ((r & 7) << 3)));
#pragma unroll
      for (int ni = 0; ni < 4; ni++) {
        acc[mi][ni] = __builtin_amdgcn_mfma_f32_16x16x32_f16(a0, bf[0][ni], acc[mi][ni], 0, 0, 0);
        acc[mi][ni] = __builtin_amdgcn_mfma_f32_16x16x32_f16(a1, bf[1][ni], acc[mi][ni], 0, 0, 0);
      }
    }
  }
#undef STAGE

  // epilogue: qkv scatter [which][b][h][s][d] (same math as before)
#pragma unroll
  for (int mi = 0; mi < 8; mi++)
#pragma unroll
    for (int ni = 0; ni < 4; ni++)
#pragma unroll
      for (int r = 0; r < 4; r++) {
        int row = m0 + wm * 128 + mi * 16 + quad * 4 + r;
        int col = n0 + wn * 64 + ni * 16 + l16;
        float v = acc[mi][ni][r];
        int which = col >> 10, h = (col >> 6) & 15, d = col & 63;
        int b = row >> 11, s = row & 2047;
        if (which == 0) v *= 0.125f;  // fold softmax scale into Q
        Ch[((((size_t)(which * 2 + b) * 16 + h) * 2048) + s) * 64 + d] = (_Float16)v;
      }
}

// ---------------- m97-style f16 MFMA GEMM (kept for proj), B^T [N][K] ----------------
template <int MODE, int BN>
__global__ __launch_bounds__(256) void gemm16(const _Float16* __restrict__ A,
                                              const _Float16* __restrict__ B,
                                              float* __restrict__ Cf,
                                              _Float16* __restrict__ Ch,
                                              int M, int N, int K) {
  constexpr int MI = (BN == 128) ? 4 : 2;
  __shared__ __align__(16) _Float16 As[128 * 32];
  __shared__ __align__(16) _Float16 Bs[BN * 32];
  const int tid = threadIdx.x;
  const int lane = tid & 63;
  const int wid = tid >> 6;
  const int quad = lane >> 4;
  const int l16 = lane & 15;
  const int mbase = (BN == 128) ? (wid >> 1) * 64 : wid * 32;
  const int nbase = (BN == 128) ? (wid & 1) * 64 : 0;
  const int m0 = blockIdx.y * 128;
  const int n0 = blockIdx.x * BN;

  f32x4 acc[MI][4];
  const f32x4 fz = {0.f, 0.f, 0.f, 0.f};
#pragma unroll
  for (int i = 0; i < MI; i++)
#pragma unroll
    for (int j = 0; j < 4; j++) acc[i][j] = fz;

  const int srow = tid >> 2;
  const int kq = (tid & 3) * 8;

  for (int kt = 0; kt < K; kt += 32) {
    gl2lds16(A + (size_t)(m0 + srow) * K + kt + kq, &As[tid * 8]);
    gl2lds16(A + (size_t)(m0 + 64 + srow) * K + kt + kq, &As[2048 + tid * 8]);
    gl2lds16(B + (size_t)(n0 + srow) * K + kt + kq, &Bs[tid * 8]);
    if (BN == 128)
      gl2lds16(B + (size_t)(n0 + 64 + srow) * K + kt + kq, &Bs[2048 + tid * 8]);
    __syncthreads();
    half8 af[MI], bf[4];
#pragma unroll
    for (int mi = 0; mi < MI; mi++)
      af[mi] = *(const half8*)&As[(mbase + mi * 16 + l16) * 32 + quad * 8];
#pragma unroll
    for (int ni = 0; ni < 4; ni++)
      bf[ni] = *(const half8*)&Bs[(nbase + ni * 16 + l16) * 32 + quad * 8];
#pragma unroll
    for (int mi = 0; mi < MI; mi++)
#pragma unroll
      for (int ni = 0; ni < 4; ni++)
        acc[mi][ni] = __builtin_amdgcn_mfma_f32_16x16x32_f16(af[mi], bf[ni], acc[mi][ni], 0, 0, 0);
    __syncthreads();
  }

#pragma unroll
  for (int mi = 0; mi < MI; mi++)
#pragma unroll
    for (int ni = 0; ni < 4; ni++)
#pragma unroll
      for (int r = 0; r < 4; r++) {
        int row = m0 + mbase + mi * 16 + quad * 4 + r;
        int col = n0 + nbase + ni * 16 + l16;
        float v = acc[mi][ni][r];
        if (MODE == 0) {
          Cf[(size_t)row * N + col] = v;
        } else {
          int which = col >> 10, h = (col >> 6) & 15, d = col & 63;
          int b = row >> 11, s = row & 2047;
          if (which == 0) v *= 0.125f;
          Ch[((((size_t)(which * 2 + b) * 16 + h) * 2048) + s) * 64 + d] = (_Float16)v;
        }
      }
}

// ---------------- fused causal attention (unchanged from R8) ----------------
__global__ __launch_bounds__(256) void attn_kernel(const _Float16* __restrict__ qkv,
                                                   const _Float16* __restrict__ vt,
                                                   float* __restrict__ w_out,
                                                   _Float16* __restrict__ o_buf) {
  const int qt = 31 - blockIdx.x;  // heavy blocks launch first
  const int bh = blockIdx.y;
  const int tid = threadIdx.x;
  const int lane = tid & 63;
  const int wid = tid >> 6;
  const int quad = lane >> 4;
  const int l16 = lane & 15;

  const _Float16* qp = qkv + (size_t)bh * 131072;
  const _Float16* kp = qp + 4194304;
  const _Float16* vtb = vt + (size_t)bh * 131072;

  __shared__ __align__(16) _Float16 Ks[2][4096];  // [buf][chunk d0/d1][s][32]
  __shared__ __align__(16) _Float16 Vs[2][4096];  // [buf][chunk s0/s1][d][32]
  __shared__ __align__(16) _Float16 Ps[64][64];   // XOR-swizzled, wave-private rows

  const int qrow = qt * 64 + wid * 16 + l16;
  const half8 qa0 = *(const half8*)(qp + qrow * 64 + quad * 8);
  const half8 qa1 = *(const half8*)(qp + qrow * 64 + 32 + quad * 8);

  const int srow = tid >> 2;        // 0..63
  const int blk8 = (tid & 3) * 8;
  const f32x4 fz = {0.f, 0.f, 0.f, 0.f};
  const int qloc = wid * 16 + l16;  // this lane's q row within the 64-row tile
  const int kbase = quad * 4;       // this lane's k sub-offset within a 16-col block

  float* wbase = w_out + (size_t)bh * 4194304 + (size_t)qt * 131072;

  // ---- zerofill above-diagonal: nt streaming stores ----
  {
    const int rr = tid >> 4, cc = (tid & 15) * 4;
    for (int kt = qt + 1; kt < 32; kt++) {
      float* wz = wbase + (size_t)kt * 64 + cc;
#pragma unroll
      for (int p = 0; p < 4; p++)
        nt_store4(wz + (size_t)(p * 16 + rr) * 2048, fz);
    }
  }

  float lsum = 0.f;

  // ---- pass 1: row sums of exp(s); K staged via gl2lds, 2-deep ----
  int cur = 0;
  gl2lds16(kp + (size_t)srow * 64 + blk8, &Ks[0][tid * 8]);
  gl2lds16(kp + (size_t)srow * 64 + 32 + blk8, &Ks[0][2048 + tid * 8]);
  __syncthreads();
  for (int kt = 0; kt <= qt; kt++) {
    if (kt < qt) {
      gl2lds16(kp + (size_t)((kt + 1) * 64 + srow) * 64 + blk8, &Ks[cur ^ 1][tid * 8]);
      gl2lds16(kp + (size_t)((kt + 1) * 64 + srow) * 64 + 32 + blk8, &Ks[cur ^ 1][2048 + tid * 8]);
    }
    f32x4 sacc[4];
    __builtin_amdgcn_s_setprio(1);
#pragma unroll
    for (int ni = 0; ni < 4; ni++) {
      half8 kb0 = *(const half8*)&Ks[cur][(ni * 16 + l16) * 32 + quad * 8];
      half8 kb1 = *(const half8*)&Ks[cur][2048 + (ni * 16 + l16) * 32 + quad * 8];
      f32x4 s = fz;
      s = __builtin_amdgcn_mfma_f32_16x16x32_f16(kb0, qa0, s, 0, 0, 0);  // swapped: S^T
      s = __builtin_amdgcn_mfma_f32_16x16x32_f16(kb1, qa1, s, 0, 0, 0);
      sacc[ni] = s;
    }
    __builtin_amdgcn_s_setprio(0);
    if (kt < qt) {
#pragma unroll
      for (int ni = 0; ni < 4; ni++)
#pragma unroll
        for (int r = 0; r < 4; r++) lsum += __expf(sacc[ni][r]);
    } else {  // diagonal tile: include only k <= q
#pragma unroll
      for (int ni = 0; ni < 4; ni++)
#pragma unroll
        for (int r = 0; r < 4; r++) {
          if (ni * 16 + kbase + r <= qloc) lsum += __expf(sacc[ni][r]);
        }
    }
    __syncthreads();
    cur ^= 1;
  }
  // reduce over the 4 quads holding the same q row
  lsum += __shfl_xor(lsum, 16);
  lsum += __shfl_xor(lsum, 32);
  const float invl = 1.0f / lsum;

  f32x4 oacc[4];
#pragma unroll
  for (int di = 0; di < 4; di++) oacc[di] = fz;

  // ---- pass 2: recompute S^T, P -> Ps, PV; w export deferred one tile ----
  cur = 0;
  gl2lds16(kp + (size_t)srow * 64 + blk8, &Ks[0][tid * 8]);
  gl2lds16(kp + (size_t)srow * 64 + 32 + blk8, &Ks[0][2048 + tid * 8]);
  gl2lds16(vtb + (size_t)srow * 2048 + blk8, &Vs[0][tid * 8]);
  gl2lds16(vtb + (size_t)srow * 2048 + 32 + blk8, &Vs[0][2048 + tid * 8]);
  __syncthreads();
  for (int kt = 0; kt <= qt; kt++) {
    // deferred export of tile kt-1: Ps stripe is wave-private and still intact;
    // stores issued here retire during this tile's compute.
    if (kt > 0) {
      const int erow = lane >> 2;
      const int ec = (lane & 3) * 4;
      const _Float16* prow = &Ps[wid * 16 + erow][0];
      float* wrow = wbase + (size_t)(wid * 16 + erow) * 2048 + (kt - 1) * 64;
#pragma unroll
      for (int j = 0; j < 4; j++) {
        half4 h = *(const half4*)(prow + PSW(erow, j * 16 + ec));
        f32x4 o;
        o[0] = (float)h[0]; o[1] = (float)h[1]; o[2] = (float)h[2]; o[3] = (float)h[3];
        nt_store4(wrow + j * 16 + ec, o);
      }
    }
    if (kt < qt) {
      const int kn = kt + 1;
      gl2lds16(kp + (size_t)(kn * 64 + srow) * 64 + blk8, &Ks[cur ^ 1][tid * 8]);
      gl2lds16(kp + (size_t)(kn * 64 + srow) * 64 + 32 + blk8, &Ks[cur ^ 1][2048 + tid * 8]);
      gl2lds16(vtb + (size_t)srow * 2048 + kn * 64 + blk8, &Vs[cur ^ 1][tid * 8]);
      gl2lds16(vtb + (size_t)srow * 2048 + kn * 64 + 32 + blk8, &Vs[cur ^ 1][2048 + tid * 8]);
    }
    f32x4 sacc[4];
    __builtin_amdgcn_s_setprio(1);
#pragma unroll
    for (int ni = 0; ni < 4; ni++) {
      half8 kb0 = *(const half8*)&Ks[cur][(ni * 16 + l16) * 32 + quad * 8];
      half8 kb1 = *(const half8*)&Ks[cur][2048 + (ni * 16 + l16) * 32 + quad * 8];
      f32x4 s = fz;
      s = __builtin_amdgcn_mfma_f32_16x16x32_f16(kb0, qa0, s, 0, 0, 0);  // swapped: S^T
      s = __builtin_amdgcn_mfma_f32_16x16x32_f16(kb1, qa1, s, 0, 0, 0);
      sacc[ni] = s;
    }
    __builtin_amdgcn_s_setprio(0);
    const bool diag = (kt == qt);
#pragma unroll
    for (int ni = 0; ni < 4; ni++) {
      half4 ph;
#pragma unroll
      for (int r = 0; r < 4; r++) {
        float p = __expf(sacc[ni][r]) * invl;
        if (diag && (ni * 16 + kbase + r > qloc)) p = 0.0f;
        ph[r] = (_Float16)p;
      }
      *(half4*)&Ps[qloc][PSW(qloc, ni * 16 + kbase)] = ph;  // wave-private row
    }
    // PV: A-frag from Ps (own stripe), B-frag from Vs
    __builtin_amdgcn_s_setprio(1);
#pragma unroll
    for (int kk = 0; kk < 2; kk++) {
      half8 pa = *(const half8*)&Ps[wid * 16 + l16][PSW(l16, kk * 32 + quad * 8)];
#pragma unroll
      for (int di = 0; di < 4; di++) {
        half8 vb = *(const half8*)&Vs[cur][kk * 2048 + (di * 16 + l16) * 32 + quad * 8];
        oacc[di] = __builtin_amdgcn_mfma_f32_16x16x32_f16(pa, vb, oacc[di], 0, 0, 0);
      }
    }
    __builtin_amdgcn_s_setprio(0);
    __syncthreads();
    cur ^= 1;
  }
  // final export: tile qt
  {
    const int erow = lane >> 2;
    const int ec = (lane & 3) * 4;
    const _Float16* prow = &Ps[wid * 16 + erow][0];
    float* wrow = wbase + (size_t)(wid * 16 + erow) * 2048 + (size_t)qt * 64;
#pragma unroll
    for (int j = 0; j < 4; j++) {
      half4 h = *(const half4*)(prow + PSW(erow, j * 16 + ec));
      f32x4 o;
      o[0] = (float)h[0]; o[1] = (float)h[1]; o[2] = (float)h[2]; o[3] = (float)h[3];
      nt_store4(wrow + j * 16 + ec, o);
    }
  }

  const int b = bh >> 4, h = bh & 15;
#pragma unroll
  for (int di = 0; di < 4; di++)
#pragma unroll
    for (int r = 0; r < 4; r++) {
      int s = qt * 64 + wid * 16 + quad * 4 + r;
      int d = di * 16 + l16;
      o_buf[((size_t)(b * 2048 + s) * 16 + h) * 64 + d] = (_Float16)oacc[di][r];
    }
}

extern "C" void kernel_launch(void* const* d_in, const int* in_sizes, int n_in,
                              void* d_out, int out_size, void* d_ws, size_t ws_size,
                              hipStream_t stream) {
  const float* x = (const float*)d_in[0];
  const float* w_qkv = (const float*)d_in[1];
  const float* w_proj = (const float*)d_in[2];
  float* out = (float*)d_out;
  float* w_attn = out + (size_t)4194304;

  // ws (bytes): x16 0..8M | wqkvT 8..14M | wprojT 14..16M | qkv 16..40M |
  //             vT 40..48M | o 48..56M
  char* ws = (char*)d_ws;
  _Float16* x16 = (_Float16*)ws;
  _Float16* wqkvT = (_Float16*)(ws + (size_t)(8 << 20));
  _Float16* wprojT = (_Float16*)(ws + (size_t)(14 << 20));
  _Float16* qkvb = (_Float16*)(ws + (size_t)(16 << 20));
  _Float16* vT = (_Float16*)(ws + (size_t)(40 << 20));
  _Float16* ob = (_Float16*)(ws + (size_t)(48 << 20));

  cvt_kernel<<<2048, 256, 0, stream>>>(x, x16, 4194304);
  cvtT_kernel<<<dim3(48, 16), 256, 0, stream>>>(w_qkv, wqkvT, 1024, 3072);
  cvtT_kernel<<<dim3(16, 16), 256, 0, stream>>>(w_proj, wprojT, 1024, 1024);

  gemmqkv<<<dim3(12, 16), 512, 0, stream>>>(x16, wqkvT, qkvb);
  vtrans_kernel<<<dim3(32, 32), 256, 0, stream>>>(qkvb + (size_t)2 * 4194304, vT);
  attn_kernel<<<dim3(32, 32), 256, 0, stream>>>(qkvb, vT, w_attn, ob);
  gemm16<0, 64><<<dim3(16, 32), 256, 0, stream>>>(ob, wprojT, out, nullptr, 4096, 1024, 1024);
}